// Round 1
// baseline (1732.927 us; speedup 1.0000x reference)
//
#include <hip/hip_runtime.h>
#include <hip/hip_fp16.h>

// Hankel MPS, round 6: persistent fused chain.
//
// prep: W1,W2 -> fp16 frag-ordered; H_mid -> frag-ordered bf16 hi/lo
// enc:  fp16 MFMA 2-layer MLP (unchanged)
// fused_chain (ONE kernel, 512 blocks, grid-barrier between steps):
//   phase 0: init v0[p][b] (blocks 0..127)
//   phase 1..10: chain step (byte-identical math to round 5; nIn=8 staging
//                fully unrolled for load ILP), device-scope sense-reversal
//                grid sync replaces kernel boundaries
//   final: sum 8 partials in LDS + H_last contraction + wave reduce -> out
// Fallback (small ws): round-5 multi-kernel atomic path, unchanged.
//
// Co-residency: __launch_bounds__(256,2) caps VGPR<=256; LDS 42.2KB ->
// 2 blocks/CU guaranteed -> 512 blocks co-resident (grid == capacity).
//
// ws (partial path, 82.0 MB): encH 25.17M | HmH 10.49M | HmL 10.49M |
//   w1f 64K | w2f 128K | v0 2M | vPartA 16.78M | vPartB 16.78M

#define B_ALL 8192
#define TT    12

typedef short bfrag __attribute__((ext_vector_type(8)));      // 8 bf16
typedef _Float16 hfrag __attribute__((ext_vector_type(8)));   // 8 fp16
typedef float ffrag __attribute__((ext_vector_type(16)));     // 32x32 C/D

#define O_ENC   0ULL
#define O_HMH   25165824ULL
#define O_HML   35651584ULL
#define O_W1F   46137344ULL
#define O_W2F   46202880ULL
#define O_V0    46333952ULL            // 2 MB (v0; reused as vT in fallback)
#define O_PA    48431104ULL            // 16 MB
#define O_PB    65208320ULL            // 16 MB
#define NEED_PARTIAL 81985536ULL
#define O_VA    48431104ULL            // atomic path: 2 MB
#define O_VB    50528256ULL            // atomic path: 2 MB

__device__ __forceinline__ unsigned short bf16_rne(float f) {
    unsigned int u = __builtin_bit_cast(unsigned int, f);
    unsigned int r = (u + 0x7fffu + ((u >> 16) & 1u)) >> 16;
    return (unsigned short)r;
}
__device__ __forceinline__ float bf16_f32(unsigned short h) {
    unsigned int u = ((unsigned int)h) << 16;
    return __builtin_bit_cast(float, u);
}

// ---------------- prep (unchanged) ----------------
__global__ __launch_bounds__(256)
void prep_kernel(const float* __restrict__ W1, const float* __restrict__ W2,
                 const float* __restrict__ Hm,
                 __half* __restrict__ w1f, __half* __restrict__ w2f,
                 unsigned short* __restrict__ Hh, unsigned short* __restrict__ Hl)
{
    const long long N_W1 = 32768, N_W2 = 65536, N_H = 10LL * 128 * 4096;
    const long long total = N_W1 + N_W2 + N_H;
    const long long stride = (long long)gridDim.x * blockDim.x;
    for (long long idx = (long long)blockIdx.x * blockDim.x + threadIdx.x;
         idx < total; idx += stride) {
        if (idx < N_W1) {
            const int w = (int)idx;
            const int jn = w >> 11, ks = (w >> 9) & 3, half = (w >> 8) & 1;
            const int jl = (w >> 3) & 31, jj = w & 7;
            const int j = jn * 32 + jl, d = ks * 16 + half * 8 + jj;
            w1f[w] = __float2half(W1[j * 64 + d]);
        } else if (idx < N_W1 + N_W2) {
            const int w = (int)(idx - N_W1);
            const int en = w >> 14, ks2g = (w >> 9) & 31, half = (w >> 8) & 1;
            const int el = (w >> 3) & 31, jj = w & 7;
            const int e = en * 32 + el, j = ks2g * 16 + half * 8 + jj;
            w2f[w] = __float2half(W2[e * 512 + j]);
        } else {
            const long long q = idx - N_W1 - N_W2;
            const int t = (int)(q / 524288);
            const int rem = (int)(q % 524288);
            const int e = rem >> 12;
            const int f = rem & 4095;
            const int mf = f >> 11, s = (f >> 9) & 3, half = (f >> 8) & 1;
            const int l = (f >> 3) & 31, j = f & 7;
            const int p = s * 16 + half * 8 + j;
            const int r = mf * 32 + l;
            const float val = Hm[(((long long)t * 64 + p) * 128 + e) * 64 + r];
            const unsigned short hi = bf16_rne(val);
            const unsigned short lo = bf16_rne(val - bf16_f32(hi));
            Hh[q] = hi;
            Hl[q] = lo;
        }
    }
}

// ---------------- encoder (unchanged) ----------------
__global__ __launch_bounds__(256)
void enc_kernel(const float* __restrict__ x,
                const float* __restrict__ b1, const float* __restrict__ b2,
                const __half* __restrict__ w1f, const __half* __restrict__ w2f,
                __half* __restrict__ encH)
{
    __shared__ __align__(16) unsigned char smem[17408];
    float* x_s  = (float*)smem;
    __half* h_s = (__half*)smem;

    const int tid   = threadIdx.x;
    const int wv    = tid >> 6;
    const int lane  = tid & 63;
    const int l32   = lane & 31;
    const int half  = lane >> 5;
    const int msub  = wv >> 1;
    const int nhalf = wv & 1;
    const int m0    = blockIdx.x * 64;

    #pragma unroll
    for (int i = 0; i < 4; ++i) {
        const int f4 = i * 256 + tid;
        const int r = f4 >> 4, c4 = (f4 & 15) * 4;
        *(float4*)&x_s[r * 68 + c4] =
            *(const float4*)&x[(long long)(m0 + r) * 64 + c4];
    }
    __syncthreads();

    hfrag xa[4];
    #pragma unroll
    for (int ks = 0; ks < 4; ++ks) {
        const float* src = &x_s[(msub * 32 + l32) * 68 + ks * 16 + half * 8];
        const float4 a = *(const float4*)src;
        const float4 b = *(const float4*)(src + 4);
        hfrag v;
        v[0] = (_Float16)a.x; v[1] = (_Float16)a.y;
        v[2] = (_Float16)a.z; v[3] = (_Float16)a.w;
        v[4] = (_Float16)b.x; v[5] = (_Float16)b.y;
        v[6] = (_Float16)b.z; v[7] = (_Float16)b.w;
        xa[ks] = v;
    }
    __syncthreads();

    ffrag c2[2];
    c2[0] = 0.0f; c2[1] = 0.0f;

    for (int chunk = 0; chunk < 4; ++chunk) {
        ffrag c1[2];
        float b1j[2];
        #pragma unroll
        for (int nf = 0; nf < 2; ++nf) {
            const int jn = chunk * 4 + nhalf * 2 + nf;
            b1j[nf] = b1[jn * 32 + l32];
            ffrag acc = 0.0f;
            #pragma unroll
            for (int ks = 0; ks < 4; ++ks) {
                const hfrag bh = *(const hfrag*)(w1f + (jn * 4 + ks) * 512
                                                 + half * 256 + l32 * 8);
                acc = __builtin_amdgcn_mfma_f32_32x32x16_f16(xa[ks], bh, acc, 0, 0, 0);
            }
            c1[nf] = acc;
        }
        __syncthreads();
        #pragma unroll
        for (int nf = 0; nf < 2; ++nf) {
            #pragma unroll
            for (int i2 = 0; i2 < 16; ++i2) {
                const int m_row = (i2 & 3) + 8 * (i2 >> 2) + 4 * half;
                const float v = fmaxf(c1[nf][i2] + b1j[nf], 0.0f);
                h_s[(msub * 32 + m_row) * 136 + nhalf * 64 + nf * 32 + l32] =
                    __float2half(v);
            }
        }
        __syncthreads();
        #pragma unroll
        for (int ks2 = 0; ks2 < 8; ++ks2) {
            const hfrag a = *(const hfrag*)&h_s[(msub * 32 + l32) * 136
                                                + ks2 * 16 + half * 8];
            const int ks2g = chunk * 8 + ks2;
            #pragma unroll
            for (int ef = 0; ef < 2; ++ef) {
                const int en = nhalf * 2 + ef;
                const hfrag b = *(const hfrag*)(w2f + (en * 32 + ks2g) * 512
                                                + half * 256 + l32 * 8);
                c2[ef] = __builtin_amdgcn_mfma_f32_32x32x16_f16(a, b, c2[ef], 0, 0, 0);
            }
        }
    }

    #pragma unroll
    for (int ef = 0; ef < 2; ++ef) {
        const int e = nhalf * 64 + ef * 32 + l32;
        const float b2e = b2[e];
        #pragma unroll
        for (int i2 = 0; i2 < 16; ++i2) {
            const int m_row = (i2 & 3) + 8 * (i2 >> 2) + 4 * half;
            const int m_g = m0 + msub * 32 + m_row;
            encH[(long long)m_g * 128 + e] =
                __float2half(fmaxf(c2[ef][i2] + b2e, 0.0f));
        }
    }
}

// ---------------- init (fallback path) ----------------
__global__ __launch_bounds__(256, 2)
void init_kernel(const __half* __restrict__ encH, const float* __restrict__ Hf,
                 float* __restrict__ vOut)   // [64][8192]
{
    __shared__ float enc_s[64 * 129];   // [b][e]
    const int tid = threadIdx.x;
    const int b0 = blockIdx.x * 64;     // grid 128
    {
        const int b = tid >> 2, ec = (tid & 3) * 32;
        const __half* er = encH + ((size_t)(b0 + b) * 12 + 0) * 128 + ec;
        #pragma unroll
        for (int q = 0; q < 4; ++q) {
            uint4 u = *(const uint4*)(er + q * 8);
            const __half* hp = (const __half*)&u;
            #pragma unroll
            for (int j = 0; j < 8; ++j)
                enc_s[b * 129 + ec + q * 8 + j] = __half2float(hp[j]);
        }
    }
    __syncthreads();
    const int wv = tid >> 6, lane = tid & 63;
    const int b = b0 + lane;
    for (int pc = 0; pc < 16; pc += 4) {
        const int p = wv * 16 + pc;
        float a0 = 0, a1 = 0, a2 = 0, a3 = 0;
        for (int e = 0; e < 128; ++e) {
            const float ev = enc_s[lane * 129 + e];
            const float4 h = *(const float4*)&Hf[e * 64 + p];   // wave-uniform
            a0 += ev * h.x; a1 += ev * h.y; a2 += ev * h.z; a3 += ev * h.w;
        }
        vOut[(size_t)(p + 0) * B_ALL + b] = a0;
        vOut[(size_t)(p + 1) * B_ALL + b] = a1;
        vOut[(size_t)(p + 2) * B_ALL + b] = a2;
        vOut[(size_t)(p + 3) * B_ALL + b] = a3;
    }
}

// ---------------- chain step (fallback path, unchanged) ----------------
__global__ __launch_bounds__(256, 2)
void chain_step(const unsigned short* __restrict__ Hsh,  // this t: [128e][4096]
                const unsigned short* __restrict__ Hsl,
                const __half* __restrict__ encH,
                const float* __restrict__ vIn, int nIn,   // nIn partials [p][b]
                float* __restrict__ vOut, int partStride, // 0 => atomicAdd flat
                int t)
{
    __shared__ float vsum[64 * 132];    // [p][b0..b0+127]
    __shared__ float enc_s[16 * 132];   // [e][b]

    const int tid = threadIdx.x;
    const int b0 = (blockIdx.x & 63) * 128;
    const int eg = blockIdx.x >> 6;
    const int e0 = eg * 16;

    #pragma unroll
    for (int k = 0; k < 8; ++k) {
        const int p  = (tid >> 5) + k * 8;
        const int bl = (tid & 31) * 4;
        float4 s = {0.f, 0.f, 0.f, 0.f};
        for (int g = 0; g < nIn; ++g) {
            const float4 u = *(const float4*)&vIn[(size_t)g * 524288
                                                  + (size_t)p * B_ALL + b0 + bl];
            s.x += u.x; s.y += u.y; s.z += u.z; s.w += u.w;
        }
        *(float4*)&vsum[p * 132 + bl] = s;
    }
    if (tid < 128) {
        const __half* er = encH + ((size_t)(b0 + tid) * 12 + t) * 128 + e0;
        uint4 u0 = *(const uint4*)er;
        uint4 u1 = *(const uint4*)(er + 8);
        const __half* h0 = (const __half*)&u0;
        const __half* h1 = (const __half*)&u1;
        #pragma unroll
        for (int el = 0; el < 8; ++el) enc_s[el * 132 + tid] = __half2float(h0[el]);
        #pragma unroll
        for (int el = 0; el < 8; ++el) enc_s[(el + 8) * 132 + tid] = __half2float(h1[el]);
    }
    __syncthreads();

    const int wv = tid >> 6, lane = tid & 63;
    const int l32 = lane & 31, half = lane >> 5;
    const int mf = wv >> 1, bh = wv & 1;

    bfrag vbh_[2][4], vbl_[2][4];
    #pragma unroll
    for (int nf = 0; nf < 2; ++nf) {
        const int bcol = bh * 64 + nf * 32 + l32;
        #pragma unroll
        for (int s = 0; s < 4; ++s) {
            const int p0 = s * 16 + half * 8;
            bfrag hb, lb;
            #pragma unroll
            for (int j = 0; j < 8; ++j) {
                const float f = vsum[(p0 + j) * 132 + bcol];
                const unsigned short hi = bf16_rne(f);
                const unsigned short lo = bf16_rne(f - bf16_f32(hi));
                hb[j] = (short)hi;
                lb[j] = (short)lo;
            }
            vbh_[nf][s] = hb;
            vbl_[nf][s] = lb;
        }
    }

    ffrag z = 0.0f;
    ffrag vn0 = 0.0f, vn1 = 0.0f;

    #pragma unroll 2
    for (int e = 0; e < 16; ++e) {
        const float ev0 = enc_s[e * 132 + bh * 64 + l32];
        const float ev1 = enc_s[e * 132 + bh * 64 + 32 + l32];
        const unsigned short* hbase = Hsh + (size_t)(e0 + e) * 4096;
        const unsigned short* lbase = Hsl + (size_t)(e0 + e) * 4096;
        ffrag wa = z, wb = z;
        #pragma unroll
        for (int s = 0; s < 4; ++s) {
            const int fo = (((mf * 4 + s) * 2 + half) * 32 + l32) * 8;
            const bfrag ah = *(const bfrag*)(hbase + fo);
            const bfrag al = *(const bfrag*)(lbase + fo);
            wa = __builtin_amdgcn_mfma_f32_32x32x16_bf16(ah, vbh_[0][s], wa, 0, 0, 0);
            wa = __builtin_amdgcn_mfma_f32_32x32x16_bf16(ah, vbl_[0][s], wa, 0, 0, 0);
            wa = __builtin_amdgcn_mfma_f32_32x32x16_bf16(al, vbh_[0][s], wa, 0, 0, 0);
            wb = __builtin_amdgcn_mfma_f32_32x32x16_bf16(ah, vbh_[1][s], wb, 0, 0, 0);
            wb = __builtin_amdgcn_mfma_f32_32x32x16_bf16(ah, vbl_[1][s], wb, 0, 0, 0);
            wb = __builtin_amdgcn_mfma_f32_32x32x16_bf16(al, vbh_[1][s], wb, 0, 0, 0);
        }
        vn0 += wa * ev0;
        vn1 += wb * ev1;
    }

    #pragma unroll
    for (int nf = 0; nf < 2; ++nf) {
        const ffrag vv = nf ? vn1 : vn0;
        const int b = b0 + bh * 64 + nf * 32 + l32;
        #pragma unroll
        for (int i = 0; i < 16; ++i) {
            const int r = mf * 32 + (i & 3) + 8 * (i >> 2) + 4 * half;
            if (partStride)
                vOut[(size_t)eg * partStride + (size_t)r * B_ALL + b] = vv[i];
            else
                atomicAdd(&vOut[(size_t)r * B_ALL + b], vv[i]);
        }
    }
}

// ---------------- reduce + transpose (fallback path) ----------------
__global__ __launch_bounds__(256)
void reduce_t_kernel(const float* __restrict__ vIn, int nIn,
                     float* __restrict__ vT)   // [8192][64]
{
    __shared__ float vt[64][68];
    const int tid = threadIdx.x;
    const int b0 = blockIdx.x * 64;   // grid 128
    #pragma unroll
    for (int k = 0; k < 8; ++k) {
        const int p  = (tid >> 5) + k * 8;
        const int bl = (tid & 31) * 2;
        float2 s = {0.f, 0.f};
        for (int g = 0; g < nIn; ++g) {
            const float2 u = *(const float2*)&vIn[(size_t)g * 524288
                                                  + (size_t)p * B_ALL + b0 + bl];
            s.x += u.x; s.y += u.y;
        }
        vt[bl][p] = s.x;
        vt[bl + 1][p] = s.y;
    }
    __syncthreads();
    const int b = tid >> 2, c = (tid & 3) * 16;
    float4* dst = (float4*)&vT[(size_t)(b0 + b) * 64 + c];
    #pragma unroll
    for (int q = 0; q < 4; ++q)
        dst[q] = *(float4*)&vt[b][c + q * 4];
}

// ---------------- final (fallback path) ----------------
__global__ __launch_bounds__(64)
void final_kernel(const __half* __restrict__ encH, const float* __restrict__ HL,
                  const float* __restrict__ vT, float* __restrict__ out)
{
    __shared__ float hl_s[64 * 129];
    const int tid = threadIdx.x;
    const int b0 = blockIdx.x * 16;
    for (int i = 0; i < 128; ++i) {
        const int idx = i * 64 + tid;
        hl_s[(idx >> 7) * 129 + (idx & 127)] = HL[idx];
    }
    __syncthreads();
    const int p = tid;
    for (int bs = 0; bs < 16; ++bs) {
        const int b = b0 + bs;
        const __half* er = encH + (size_t)(b * 12 + 11) * 128;
        float L = 0.0f;
        #pragma unroll 16
        for (int e = 0; e < 128; ++e)
            L += __half2float(er[e]) * hl_s[p * 129 + e];
        float pre = vT[(size_t)b * 64 + p] * L;
        #pragma unroll
        for (int off = 32; off > 0; off >>= 1)
            pre += __shfl_down(pre, off);
        if (tid == 0) out[b] = pre;
    }
}

// ---------------- persistent fused chain ----------------
// Sense-reversal grid barrier. State in __device__ globals: gen monotonically
// increases across syncs/launches; bar always returns to 0 -> no reset needed.
#define NB_FUSED 512

__device__ unsigned int g_bar = 0u;
__device__ unsigned int g_gen = 0u;

__device__ __forceinline__ void grid_sync_512() {
    __syncthreads();
    if (threadIdx.x == 0) {
        __threadfence();   // agent-scope release of all prior writes
        const unsigned g =
            __hip_atomic_load(&g_gen, __ATOMIC_RELAXED, __HIP_MEMORY_SCOPE_AGENT);
        const unsigned a =
            __hip_atomic_fetch_add(&g_bar, 1u, __ATOMIC_ACQ_REL,
                                   __HIP_MEMORY_SCOPE_AGENT);
        if (a == NB_FUSED - 1u) {
            __hip_atomic_store(&g_bar, 0u, __ATOMIC_RELAXED,
                               __HIP_MEMORY_SCOPE_AGENT);
            __hip_atomic_store(&g_gen, g + 1u, __ATOMIC_RELEASE,
                               __HIP_MEMORY_SCOPE_AGENT);
        } else {
            while (__hip_atomic_load(&g_gen, __ATOMIC_ACQUIRE,
                                     __HIP_MEMORY_SCOPE_AGENT) == g)
                __builtin_amdgcn_s_sleep(2);
        }
        __threadfence();   // agent-scope acquire before post-barrier reads
    }
    __syncthreads();
}

__global__ __launch_bounds__(256, 2)
void fused_chain(const unsigned short* __restrict__ HmH,
                 const unsigned short* __restrict__ HmL,
                 const __half* __restrict__ encH,
                 const float* __restrict__ Hf,
                 const float* __restrict__ HL,
                 float* v0, float* pA, float* pB,
                 float* __restrict__ out)
{
    // LDS overlays: chain: vsum[64][132] (33792 B) + enc[16][132] (8448 B)
    //               init:  enc[64][129] (33024 B)
    //               final: hl[64][129] (33024 B) + vs[64][17] (4352 B)
    __shared__ __align__(16) unsigned char smem[42240];
    const int tid = threadIdx.x;
    const int bid = blockIdx.x;

    // ---- phase 0: init v0 (blocks 0..127) ----
    if (bid < 128) {
        float* encs = (float*)smem;        // [64][129]
        const int b0i = bid * 64;
        {
            const int b = tid >> 2, ec = (tid & 3) * 32;
            const __half* er = encH + ((size_t)(b0i + b) * 12 + 0) * 128 + ec;
            #pragma unroll
            for (int q = 0; q < 4; ++q) {
                uint4 u = *(const uint4*)(er + q * 8);
                const __half* hp = (const __half*)&u;
                #pragma unroll
                for (int j = 0; j < 8; ++j)
                    encs[b * 129 + ec + q * 8 + j] = __half2float(hp[j]);
            }
        }
        __syncthreads();
        const int wvi = tid >> 6, lanei = tid & 63;
        const int b = b0i + lanei;
        for (int pc = 0; pc < 16; pc += 4) {
            const int p = wvi * 16 + pc;
            float a0 = 0, a1 = 0, a2 = 0, a3 = 0;
            for (int e = 0; e < 128; ++e) {
                const float ev = encs[lanei * 129 + e];
                const float4 h = *(const float4*)&Hf[e * 64 + p];  // wave-uniform
                a0 += ev * h.x; a1 += ev * h.y; a2 += ev * h.z; a3 += ev * h.w;
            }
            v0[(size_t)(p + 0) * B_ALL + b] = a0;
            v0[(size_t)(p + 1) * B_ALL + b] = a1;
            v0[(size_t)(p + 2) * B_ALL + b] = a2;
            v0[(size_t)(p + 3) * B_ALL + b] = a3;
        }
    }
    grid_sync_512();

    // ---- phases 1..10: chain ----
    const int b0 = (bid & 63) * 128;
    const int eg = bid >> 6;
    const int e0 = eg * 16;
    const int wv = tid >> 6, lane = tid & 63;
    const int l32 = lane & 31, half = lane >> 5;
    const int mf = wv >> 1, bh = wv & 1;

    float* vsum  = (float*)smem;               // [64][132]
    float* encs2 = (float*)(smem + 33792);     // [16][132]

    const float* vIn = v0;
    float* vOut = pA;
    int nIn = 1;
    const unsigned short* Hsh = HmH;
    const unsigned short* Hsl = HmL;

    #pragma unroll 1
    for (int t = 1; t <= 10; ++t) {
        // stage vsum (nIn=8 fully unrolled -> 64 independent loads in flight)
        if (nIn == 1) {
            #pragma unroll
            for (int k = 0; k < 8; ++k) {
                const int p  = (tid >> 5) + k * 8;
                const int bl = (tid & 31) * 4;
                *(float4*)&vsum[p * 132 + bl] =
                    *(const float4*)&vIn[(size_t)p * B_ALL + b0 + bl];
            }
        } else {
            #pragma unroll
            for (int k = 0; k < 8; ++k) {
                const int p  = (tid >> 5) + k * 8;
                const int bl = (tid & 31) * 4;
                float4 s = {0.f, 0.f, 0.f, 0.f};
                #pragma unroll
                for (int g = 0; g < 8; ++g) {
                    const float4 u = *(const float4*)&vIn[(size_t)g * 524288
                                                          + (size_t)p * B_ALL + b0 + bl];
                    s.x += u.x; s.y += u.y; s.z += u.z; s.w += u.w;
                }
                *(float4*)&vsum[p * 132 + bl] = s;
            }
        }
        // stage enc slice [16 e][128 b]
        if (tid < 128) {
            const __half* er = encH + ((size_t)(b0 + tid) * 12 + t) * 128 + e0;
            uint4 u0 = *(const uint4*)er;
            uint4 u1 = *(const uint4*)(er + 8);
            const __half* h0 = (const __half*)&u0;
            const __half* h1 = (const __half*)&u1;
            #pragma unroll
            for (int el = 0; el < 8; ++el)
                encs2[el * 132 + tid] = __half2float(h0[el]);
            #pragma unroll
            for (int el = 0; el < 8; ++el)
                encs2[(el + 8) * 132 + tid] = __half2float(h1[el]);
        }
        __syncthreads();

        // B-frags: v hi/lo split from LDS (held in registers)
        bfrag vbh_[2][4], vbl_[2][4];
        #pragma unroll
        for (int nf = 0; nf < 2; ++nf) {
            const int bcol = bh * 64 + nf * 32 + l32;
            #pragma unroll
            for (int s = 0; s < 4; ++s) {
                const int p0 = s * 16 + half * 8;
                bfrag hb, lb;
                #pragma unroll
                for (int j = 0; j < 8; ++j) {
                    const float f = vsum[(p0 + j) * 132 + bcol];
                    const unsigned short hi = bf16_rne(f);
                    const unsigned short lo = bf16_rne(f - bf16_f32(hi));
                    hb[j] = (short)hi;
                    lb[j] = (short)lo;
                }
                vbh_[nf][s] = hb;
                vbl_[nf][s] = lb;
            }
        }

        ffrag z = 0.0f;
        ffrag vn0 = 0.0f, vn1 = 0.0f;

        #pragma unroll 2
        for (int e = 0; e < 16; ++e) {
            const float ev0 = encs2[e * 132 + bh * 64 + l32];
            const float ev1 = encs2[e * 132 + bh * 64 + 32 + l32];
            const unsigned short* hbase = Hsh + (size_t)(e0 + e) * 4096;
            const unsigned short* lbase = Hsl + (size_t)(e0 + e) * 4096;
            ffrag wa = z, wb = z;
            #pragma unroll
            for (int s = 0; s < 4; ++s) {
                const int fo = (((mf * 4 + s) * 2 + half) * 32 + l32) * 8;
                const bfrag ah = *(const bfrag*)(hbase + fo);
                const bfrag al = *(const bfrag*)(lbase + fo);
                wa = __builtin_amdgcn_mfma_f32_32x32x16_bf16(ah, vbh_[0][s], wa, 0, 0, 0);
                wa = __builtin_amdgcn_mfma_f32_32x32x16_bf16(ah, vbl_[0][s], wa, 0, 0, 0);
                wa = __builtin_amdgcn_mfma_f32_32x32x16_bf16(al, vbh_[0][s], wa, 0, 0, 0);
                wb = __builtin_amdgcn_mfma_f32_32x32x16_bf16(ah, vbh_[1][s], wb, 0, 0, 0);
                wb = __builtin_amdgcn_mfma_f32_32x32x16_bf16(ah, vbl_[1][s], wb, 0, 0, 0);
                wb = __builtin_amdgcn_mfma_f32_32x32x16_bf16(al, vbh_[1][s], wb, 0, 0, 0);
            }
            vn0 += wa * ev0;
            vn1 += wb * ev1;
        }

        // epilogue: private partial slice (coalesced)
        #pragma unroll
        for (int nf = 0; nf < 2; ++nf) {
            const ffrag vv = nf ? vn1 : vn0;
            const int b = b0 + bh * 64 + nf * 32 + l32;
            #pragma unroll
            for (int i = 0; i < 16; ++i) {
                const int r = mf * 32 + (i & 3) + 8 * (i >> 2) + 4 * half;
                vOut[(size_t)eg * 524288 + (size_t)r * B_ALL + b] = vv[i];
            }
        }

        grid_sync_512();

        vIn = vOut;
        vOut = (t & 1) ? pB : pA;
        nIn = 8;
        Hsh += 524288;
        Hsl += 524288;
    }

    // ---- final: all 512 blocks, 16 b each; partial-sum fused (no vT) ----
    {
        float* hl_s = (float*)smem;              // [64][129]
        float* vs   = (float*)(smem + 33024);    // [64][17]
        const float* vFin = pB;                  // t=10 (even) wrote pB
        const int fb0 = bid * 16;
        #pragma unroll
        for (int i = 0; i < 32; ++i) {
            const int idx = i * 256 + tid;       // 8192 floats of HL
            hl_s[(idx >> 7) * 129 + (idx & 127)] = HL[idx];
        }
        {
            const int p  = tid >> 2;
            const int bs = (tid & 3) * 4;
            float4 s = {0.f, 0.f, 0.f, 0.f};
            #pragma unroll
            for (int g = 0; g < 8; ++g) {
                const float4 u = *(const float4*)&vFin[(size_t)g * 524288
                                                       + (size_t)p * B_ALL + fb0 + bs];
                s.x += u.x; s.y += u.y; s.z += u.z; s.w += u.w;
            }
            vs[p * 17 + bs + 0] = s.x;
            vs[p * 17 + bs + 1] = s.y;
            vs[p * 17 + bs + 2] = s.z;
            vs[p * 17 + bs + 3] = s.w;
        }
        __syncthreads();
        const int wv2 = tid >> 6, lane2 = tid & 63;
        #pragma unroll
        for (int q = 0; q < 4; ++q) {
            const int bl = wv2 * 4 + q;
            const __half* er = encH + ((size_t)(fb0 + bl) * 12 + 11) * 128;
            float L = 0.0f;
            #pragma unroll 16
            for (int e = 0; e < 128; ++e)
                L += __half2float(er[e]) * hl_s[lane2 * 129 + e];
            float pre = vs[lane2 * 17 + bl] * L;
            #pragma unroll
            for (int off = 32; off > 0; off >>= 1)
                pre += __shfl_down(pre, off);
            if (lane2 == 0) out[fb0 + bl] = pre;
        }
    }
}

extern "C" void kernel_launch(void* const* d_in, const int* in_sizes, int n_in,
                              void* d_out, int out_size, void* d_ws, size_t ws_size,
                              hipStream_t stream) {
    const float* x  = (const float*)d_in[0];
    const float* W1 = (const float*)d_in[1];
    const float* b1 = (const float*)d_in[2];
    const float* W2 = (const float*)d_in[3];
    const float* b2 = (const float*)d_in[4];
    const float* Hf = (const float*)d_in[5];
    const float* Hm = (const float*)d_in[6];
    const float* HL = (const float*)d_in[7];
    float* out = (float*)d_out;
    (void)in_sizes; (void)n_in; (void)out_size;

    char* ws = (char*)d_ws;
    __half* encH        = (__half*)(ws + O_ENC);
    unsigned short* HmH = (unsigned short*)(ws + O_HMH);
    unsigned short* HmL = (unsigned short*)(ws + O_HML);
    __half* w1f         = (__half*)(ws + O_W1F);
    __half* w2f         = (__half*)(ws + O_W2F);
    float* v0           = (float*)(ws + O_V0);
    float* vT           = (float*)(ws + O_V0);   // fallback alias

    const bool part = (ws_size >= NEED_PARTIAL);

    prep_kernel<<<dim3(5216), dim3(256), 0, stream>>>(W1, W2, Hm, w1f, w2f, HmH, HmL);
    enc_kernel<<<dim3(1536), dim3(256), 0, stream>>>(x, b1, b2, w1f, w2f, encH);

    if (part) {
        float* pA = (float*)(ws + O_PA);
        float* pB = (float*)(ws + O_PB);
        fused_chain<<<dim3(512), dim3(256), 0, stream>>>(
            HmH, HmL, encH, Hf, HL, v0, pA, pB, out);
    } else {
        init_kernel<<<dim3(128), dim3(256), 0, stream>>>(encH, Hf, v0);
        float* vA = (float*)(ws + O_VA);
        float* vB = (float*)(ws + O_VB);
        const float* cur = v0;
        for (int t = 1; t <= 10; ++t) {
            float* nxt = (t & 1) ? vA : vB;
            hipMemsetAsync(nxt, 0, (size_t)64 * B_ALL * sizeof(float), stream);
            chain_step<<<dim3(512), dim3(256), 0, stream>>>(
                HmH + (size_t)(t - 1) * 524288, HmL + (size_t)(t - 1) * 524288,
                encH, cur, 1, nxt, 0, t);
            cur = nxt;
        }
        reduce_t_kernel<<<dim3(128), dim3(256), 0, stream>>>(cur, 1, vT);
        final_kernel<<<dim3(512), dim3(64), 0, stream>>>(encH, HL, vT, out);
    }
}

// Round 2
// 1146.402 us; speedup vs baseline: 1.5116x; 1.5116x over previous
//
#include <hip/hip_runtime.h>
#include <hip/hip_fp16.h>

// Hankel MPS, round 7: persistent fused chain, poison-free barrier.
//
// Round-6 post-mortem: ACQUIRE polling loads emitted buffer_inv sc1 (whole-XCD
// L2 invalidate) EVERY spin iteration; __threadfence + acq_rel RMW added more
// wbl2/inv pairs. 512 spinners poisoned the L2 of still-working tail blocks ->
// latency feedback loop (1691us, MfmaUtil 6.2%).
//
// Round-7 changes:
//  - Barrier: relaxed polls (sc1 load, NO inv); one release fence before
//    arrival (wbl2, publishes partials); one acquire fence after barrier
//    completion (inv happens only when no block is mid-step).
//  - Chain: 256 blocks x 512 threads (8 waves = 2 e-groups of 16 e sharing one
//    vsum stage; in-LDS combine) -> 4 partials instead of 8: halves partial
//    traffic, doubles waves/SIMD (2->4, VGPR 128 @ launch_bounds(512,4)).
//
// ws layout unchanged (partial path 82.0 MB).

#define B_ALL 8192
#define TT    12

typedef short bfrag __attribute__((ext_vector_type(8)));      // 8 bf16
typedef _Float16 hfrag __attribute__((ext_vector_type(8)));   // 8 fp16
typedef float ffrag __attribute__((ext_vector_type(16)));     // 32x32 C/D

#define O_ENC   0ULL
#define O_HMH   25165824ULL
#define O_HML   35651584ULL
#define O_W1F   46137344ULL
#define O_W2F   46202880ULL
#define O_V0    46333952ULL            // 2 MB (v0; reused as vT in fallback)
#define O_PA    48431104ULL            // 16 MB reserved (4x2MB used)
#define O_PB    65208320ULL            // 16 MB reserved (4x2MB used)
#define NEED_PARTIAL 81985536ULL
#define O_VA    48431104ULL            // atomic path: 2 MB
#define O_VB    50528256ULL            // atomic path: 2 MB

__device__ __forceinline__ unsigned short bf16_rne(float f) {
    unsigned int u = __builtin_bit_cast(unsigned int, f);
    unsigned int r = (u + 0x7fffu + ((u >> 16) & 1u)) >> 16;
    return (unsigned short)r;
}
__device__ __forceinline__ float bf16_f32(unsigned short h) {
    unsigned int u = ((unsigned int)h) << 16;
    return __builtin_bit_cast(float, u);
}

// ---------------- prep (unchanged) ----------------
__global__ __launch_bounds__(256)
void prep_kernel(const float* __restrict__ W1, const float* __restrict__ W2,
                 const float* __restrict__ Hm,
                 __half* __restrict__ w1f, __half* __restrict__ w2f,
                 unsigned short* __restrict__ Hh, unsigned short* __restrict__ Hl)
{
    const long long N_W1 = 32768, N_W2 = 65536, N_H = 10LL * 128 * 4096;
    const long long total = N_W1 + N_W2 + N_H;
    const long long stride = (long long)gridDim.x * blockDim.x;
    for (long long idx = (long long)blockIdx.x * blockDim.x + threadIdx.x;
         idx < total; idx += stride) {
        if (idx < N_W1) {
            const int w = (int)idx;
            const int jn = w >> 11, ks = (w >> 9) & 3, half = (w >> 8) & 1;
            const int jl = (w >> 3) & 31, jj = w & 7;
            const int j = jn * 32 + jl, d = ks * 16 + half * 8 + jj;
            w1f[w] = __float2half(W1[j * 64 + d]);
        } else if (idx < N_W1 + N_W2) {
            const int w = (int)(idx - N_W1);
            const int en = w >> 14, ks2g = (w >> 9) & 31, half = (w >> 8) & 1;
            const int el = (w >> 3) & 31, jj = w & 7;
            const int e = en * 32 + el, j = ks2g * 16 + half * 8 + jj;
            w2f[w] = __float2half(W2[e * 512 + j]);
        } else {
            const long long q = idx - N_W1 - N_W2;
            const int t = (int)(q / 524288);
            const int rem = (int)(q % 524288);
            const int e = rem >> 12;
            const int f = rem & 4095;
            const int mf = f >> 11, s = (f >> 9) & 3, half = (f >> 8) & 1;
            const int l = (f >> 3) & 31, j = f & 7;
            const int p = s * 16 + half * 8 + j;
            const int r = mf * 32 + l;
            const float val = Hm[(((long long)t * 64 + p) * 128 + e) * 64 + r];
            const unsigned short hi = bf16_rne(val);
            const unsigned short lo = bf16_rne(val - bf16_f32(hi));
            Hh[q] = hi;
            Hl[q] = lo;
        }
    }
}

// ---------------- encoder (unchanged) ----------------
__global__ __launch_bounds__(256)
void enc_kernel(const float* __restrict__ x,
                const float* __restrict__ b1, const float* __restrict__ b2,
                const __half* __restrict__ w1f, const __half* __restrict__ w2f,
                __half* __restrict__ encH)
{
    __shared__ __align__(16) unsigned char smem[17408];
    float* x_s  = (float*)smem;
    __half* h_s = (__half*)smem;

    const int tid   = threadIdx.x;
    const int wv    = tid >> 6;
    const int lane  = tid & 63;
    const int l32   = lane & 31;
    const int half  = lane >> 5;
    const int msub  = wv >> 1;
    const int nhalf = wv & 1;
    const int m0    = blockIdx.x * 64;

    #pragma unroll
    for (int i = 0; i < 4; ++i) {
        const int f4 = i * 256 + tid;
        const int r = f4 >> 4, c4 = (f4 & 15) * 4;
        *(float4*)&x_s[r * 68 + c4] =
            *(const float4*)&x[(long long)(m0 + r) * 64 + c4];
    }
    __syncthreads();

    hfrag xa[4];
    #pragma unroll
    for (int ks = 0; ks < 4; ++ks) {
        const float* src = &x_s[(msub * 32 + l32) * 68 + ks * 16 + half * 8];
        const float4 a = *(const float4*)src;
        const float4 b = *(const float4*)(src + 4);
        hfrag v;
        v[0] = (_Float16)a.x; v[1] = (_Float16)a.y;
        v[2] = (_Float16)a.z; v[3] = (_Float16)a.w;
        v[4] = (_Float16)b.x; v[5] = (_Float16)b.y;
        v[6] = (_Float16)b.z; v[7] = (_Float16)b.w;
        xa[ks] = v;
    }
    __syncthreads();

    ffrag c2[2];
    c2[0] = 0.0f; c2[1] = 0.0f;

    for (int chunk = 0; chunk < 4; ++chunk) {
        ffrag c1[2];
        float b1j[2];
        #pragma unroll
        for (int nf = 0; nf < 2; ++nf) {
            const int jn = chunk * 4 + nhalf * 2 + nf;
            b1j[nf] = b1[jn * 32 + l32];
            ffrag acc = 0.0f;
            #pragma unroll
            for (int ks = 0; ks < 4; ++ks) {
                const hfrag bh = *(const hfrag*)(w1f + (jn * 4 + ks) * 512
                                                 + half * 256 + l32 * 8);
                acc = __builtin_amdgcn_mfma_f32_32x32x16_f16(xa[ks], bh, acc, 0, 0, 0);
            }
            c1[nf] = acc;
        }
        __syncthreads();
        #pragma unroll
        for (int nf = 0; nf < 2; ++nf) {
            #pragma unroll
            for (int i2 = 0; i2 < 16; ++i2) {
                const int m_row = (i2 & 3) + 8 * (i2 >> 2) + 4 * half;
                const float v = fmaxf(c1[nf][i2] + b1j[nf], 0.0f);
                h_s[(msub * 32 + m_row) * 136 + nhalf * 64 + nf * 32 + l32] =
                    __float2half(v);
            }
        }
        __syncthreads();
        #pragma unroll
        for (int ks2 = 0; ks2 < 8; ++ks2) {
            const hfrag a = *(const hfrag*)&h_s[(msub * 32 + l32) * 136
                                                + ks2 * 16 + half * 8];
            const int ks2g = chunk * 8 + ks2;
            #pragma unroll
            for (int ef = 0; ef < 2; ++ef) {
                const int en = nhalf * 2 + ef;
                const hfrag b = *(const hfrag*)(w2f + (en * 32 + ks2g) * 512
                                                + half * 256 + l32 * 8);
                c2[ef] = __builtin_amdgcn_mfma_f32_32x32x16_f16(a, b, c2[ef], 0, 0, 0);
            }
        }
    }

    #pragma unroll
    for (int ef = 0; ef < 2; ++ef) {
        const int e = nhalf * 64 + ef * 32 + l32;
        const float b2e = b2[e];
        #pragma unroll
        for (int i2 = 0; i2 < 16; ++i2) {
            const int m_row = (i2 & 3) + 8 * (i2 >> 2) + 4 * half;
            const int m_g = m0 + msub * 32 + m_row;
            encH[(long long)m_g * 128 + e] =
                __float2half(fmaxf(c2[ef][i2] + b2e, 0.0f));
        }
    }
}

// ---------------- init (fallback path) ----------------
__global__ __launch_bounds__(256, 2)
void init_kernel(const __half* __restrict__ encH, const float* __restrict__ Hf,
                 float* __restrict__ vOut)   // [64][8192]
{
    __shared__ float enc_s[64 * 129];   // [b][e]
    const int tid = threadIdx.x;
    const int b0 = blockIdx.x * 64;     // grid 128
    {
        const int b = tid >> 2, ec = (tid & 3) * 32;
        const __half* er = encH + ((size_t)(b0 + b) * 12 + 0) * 128 + ec;
        #pragma unroll
        for (int q = 0; q < 4; ++q) {
            uint4 u = *(const uint4*)(er + q * 8);
            const __half* hp = (const __half*)&u;
            #pragma unroll
            for (int j = 0; j < 8; ++j)
                enc_s[b * 129 + ec + q * 8 + j] = __half2float(hp[j]);
        }
    }
    __syncthreads();
    const int wv = tid >> 6, lane = tid & 63;
    const int b = b0 + lane;
    for (int pc = 0; pc < 16; pc += 4) {
        const int p = wv * 16 + pc;
        float a0 = 0, a1 = 0, a2 = 0, a3 = 0;
        for (int e = 0; e < 128; ++e) {
            const float ev = enc_s[lane * 129 + e];
            const float4 h = *(const float4*)&Hf[e * 64 + p];   // wave-uniform
            a0 += ev * h.x; a1 += ev * h.y; a2 += ev * h.z; a3 += ev * h.w;
        }
        vOut[(size_t)(p + 0) * B_ALL + b] = a0;
        vOut[(size_t)(p + 1) * B_ALL + b] = a1;
        vOut[(size_t)(p + 2) * B_ALL + b] = a2;
        vOut[(size_t)(p + 3) * B_ALL + b] = a3;
    }
}

// ---------------- chain step (fallback path, unchanged) ----------------
__global__ __launch_bounds__(256, 2)
void chain_step(const unsigned short* __restrict__ Hsh,  // this t: [128e][4096]
                const unsigned short* __restrict__ Hsl,
                const __half* __restrict__ encH,
                const float* __restrict__ vIn, int nIn,   // nIn partials [p][b]
                float* __restrict__ vOut, int partStride, // 0 => atomicAdd flat
                int t)
{
    __shared__ float vsum[64 * 132];    // [p][b0..b0+127]
    __shared__ float enc_s[16 * 132];   // [e][b]

    const int tid = threadIdx.x;
    const int b0 = (blockIdx.x & 63) * 128;
    const int eg = blockIdx.x >> 6;
    const int e0 = eg * 16;

    #pragma unroll
    for (int k = 0; k < 8; ++k) {
        const int p  = (tid >> 5) + k * 8;
        const int bl = (tid & 31) * 4;
        float4 s = {0.f, 0.f, 0.f, 0.f};
        for (int g = 0; g < nIn; ++g) {
            const float4 u = *(const float4*)&vIn[(size_t)g * 524288
                                                  + (size_t)p * B_ALL + b0 + bl];
            s.x += u.x; s.y += u.y; s.z += u.z; s.w += u.w;
        }
        *(float4*)&vsum[p * 132 + bl] = s;
    }
    if (tid < 128) {
        const __half* er = encH + ((size_t)(b0 + tid) * 12 + t) * 128 + e0;
        uint4 u0 = *(const uint4*)er;
        uint4 u1 = *(const uint4*)(er + 8);
        const __half* h0 = (const __half*)&u0;
        const __half* h1 = (const __half*)&u1;
        #pragma unroll
        for (int el = 0; el < 8; ++el) enc_s[el * 132 + tid] = __half2float(h0[el]);
        #pragma unroll
        for (int el = 0; el < 8; ++el) enc_s[(el + 8) * 132 + tid] = __half2float(h1[el]);
    }
    __syncthreads();

    const int wv = tid >> 6, lane = tid & 63;
    const int l32 = lane & 31, half = lane >> 5;
    const int mf = wv >> 1, bh = wv & 1;

    bfrag vbh_[2][4], vbl_[2][4];
    #pragma unroll
    for (int nf = 0; nf < 2; ++nf) {
        const int bcol = bh * 64 + nf * 32 + l32;
        #pragma unroll
        for (int s = 0; s < 4; ++s) {
            const int p0 = s * 16 + half * 8;
            bfrag hb, lb;
            #pragma unroll
            for (int j = 0; j < 8; ++j) {
                const float f = vsum[(p0 + j) * 132 + bcol];
                const unsigned short hi = bf16_rne(f);
                const unsigned short lo = bf16_rne(f - bf16_f32(hi));
                hb[j] = (short)hi;
                lb[j] = (short)lo;
            }
            vbh_[nf][s] = hb;
            vbl_[nf][s] = lb;
        }
    }

    ffrag z = 0.0f;
    ffrag vn0 = 0.0f, vn1 = 0.0f;

    #pragma unroll 2
    for (int e = 0; e < 16; ++e) {
        const float ev0 = enc_s[e * 132 + bh * 64 + l32];
        const float ev1 = enc_s[e * 132 + bh * 64 + 32 + l32];
        const unsigned short* hbase = Hsh + (size_t)(e0 + e) * 4096;
        const unsigned short* lbase = Hsl + (size_t)(e0 + e) * 4096;
        ffrag wa = z, wb = z;
        #pragma unroll
        for (int s = 0; s < 4; ++s) {
            const int fo = (((mf * 4 + s) * 2 + half) * 32 + l32) * 8;
            const bfrag ah = *(const bfrag*)(hbase + fo);
            const bfrag al = *(const bfrag*)(lbase + fo);
            wa = __builtin_amdgcn_mfma_f32_32x32x16_bf16(ah, vbh_[0][s], wa, 0, 0, 0);
            wa = __builtin_amdgcn_mfma_f32_32x32x16_bf16(ah, vbl_[0][s], wa, 0, 0, 0);
            wa = __builtin_amdgcn_mfma_f32_32x32x16_bf16(al, vbh_[0][s], wa, 0, 0, 0);
            wb = __builtin_amdgcn_mfma_f32_32x32x16_bf16(ah, vbh_[1][s], wb, 0, 0, 0);
            wb = __builtin_amdgcn_mfma_f32_32x32x16_bf16(ah, vbl_[1][s], wb, 0, 0, 0);
            wb = __builtin_amdgcn_mfma_f32_32x32x16_bf16(al, vbh_[1][s], wb, 0, 0, 0);
        }
        vn0 += wa * ev0;
        vn1 += wb * ev1;
    }

    #pragma unroll
    for (int nf = 0; nf < 2; ++nf) {
        const ffrag vv = nf ? vn1 : vn0;
        const int b = b0 + bh * 64 + nf * 32 + l32;
        #pragma unroll
        for (int i = 0; i < 16; ++i) {
            const int r = mf * 32 + (i & 3) + 8 * (i >> 2) + 4 * half;
            if (partStride)
                vOut[(size_t)eg * partStride + (size_t)r * B_ALL + b] = vv[i];
            else
                atomicAdd(&vOut[(size_t)r * B_ALL + b], vv[i]);
        }
    }
}

// ---------------- reduce + transpose (fallback path) ----------------
__global__ __launch_bounds__(256)
void reduce_t_kernel(const float* __restrict__ vIn, int nIn,
                     float* __restrict__ vT)   // [8192][64]
{
    __shared__ float vt[64][68];
    const int tid = threadIdx.x;
    const int b0 = blockIdx.x * 64;   // grid 128
    #pragma unroll
    for (int k = 0; k < 8; ++k) {
        const int p  = (tid >> 5) + k * 8;
        const int bl = (tid & 31) * 2;
        float2 s = {0.f, 0.f};
        for (int g = 0; g < nIn; ++g) {
            const float2 u = *(const float2*)&vIn[(size_t)g * 524288
                                                  + (size_t)p * B_ALL + b0 + bl];
            s.x += u.x; s.y += u.y;
        }
        vt[bl][p] = s.x;
        vt[bl + 1][p] = s.y;
    }
    __syncthreads();
    const int b = tid >> 2, c = (tid & 3) * 16;
    float4* dst = (float4*)&vT[(size_t)(b0 + b) * 64 + c];
    #pragma unroll
    for (int q = 0; q < 4; ++q)
        dst[q] = *(float4*)&vt[b][c + q * 4];
}

// ---------------- final (fallback path) ----------------
__global__ __launch_bounds__(64)
void final_kernel(const __half* __restrict__ encH, const float* __restrict__ HL,
                  const float* __restrict__ vT, float* __restrict__ out)
{
    __shared__ float hl_s[64 * 129];
    const int tid = threadIdx.x;
    const int b0 = blockIdx.x * 16;
    for (int i = 0; i < 128; ++i) {
        const int idx = i * 64 + tid;
        hl_s[(idx >> 7) * 129 + (idx & 127)] = HL[idx];
    }
    __syncthreads();
    const int p = tid;
    for (int bs = 0; bs < 16; ++bs) {
        const int b = b0 + bs;
        const __half* er = encH + (size_t)(b * 12 + 11) * 128;
        float L = 0.0f;
        #pragma unroll 16
        for (int e = 0; e < 128; ++e)
            L += __half2float(er[e]) * hl_s[p * 129 + e];
        float pre = vT[(size_t)b * 64 + p] * L;
        #pragma unroll
        for (int off = 32; off > 0; off >>= 1)
            pre += __shfl_down(pre, off);
        if (tid == 0) out[b] = pre;
    }
}

// ---------------- persistent fused chain ----------------
// Poison-free sense-reversal grid barrier:
//  - arrivals: ONE release fence (wbl2) then RELAXED fetch_add
//  - waiters:  RELAXED polls (sc1 load only, NO buffer_inv per iteration)
//  - acquire:  ONE fence per block AFTER the barrier completes (inv is
//              harmless then: no block is mid-step)
//  - last arriver: fence(acq_rel) acquires all releases via the g_bar RMW
//    release-sequence, then RELEASE-stores the new generation.
#define NB_FUSED 256

__device__ unsigned int g_bar = 0u;
__device__ unsigned int g_gen = 0u;

__device__ __forceinline__ void grid_sync_fused() {
    __syncthreads();
    if (threadIdx.x == 0) {
        __builtin_amdgcn_fence(__ATOMIC_RELEASE, "agent");   // wbl2: publish stores
        const unsigned g =
            __hip_atomic_load(&g_gen, __ATOMIC_RELAXED, __HIP_MEMORY_SCOPE_AGENT);
        const unsigned a =
            __hip_atomic_fetch_add(&g_bar, 1u, __ATOMIC_RELAXED,
                                   __HIP_MEMORY_SCOPE_AGENT);
        if (a == NB_FUSED - 1u) {
            __hip_atomic_store(&g_bar, 0u, __ATOMIC_RELAXED,
                               __HIP_MEMORY_SCOPE_AGENT);
            __builtin_amdgcn_fence(__ATOMIC_ACQ_REL, "agent"); // acquire all releases
            __hip_atomic_store(&g_gen, g + 1u, __ATOMIC_RELEASE,
                               __HIP_MEMORY_SCOPE_AGENT);
        } else {
            while (__hip_atomic_load(&g_gen, __ATOMIC_RELAXED,
                                     __HIP_MEMORY_SCOPE_AGENT) == g)
                __builtin_amdgcn_s_sleep(2);
            __builtin_amdgcn_fence(__ATOMIC_ACQUIRE, "agent"); // single inv, post-barrier
        }
    }
    __syncthreads();
}

// 256 blocks x 512 threads (8 waves). Block = (btile: 128 b) x (egp: 32 e).
// Waves: eh = wv>>2 (16-e half), mf = (wv>>1)&1 (r half), bh = wv&1 (b half).
// 4 partials (egp 0..3), stride 524288 floats each.
__global__ __launch_bounds__(512, 4)
void fused_chain(const unsigned short* __restrict__ HmH,
                 const unsigned short* __restrict__ HmL,
                 const __half* __restrict__ encH,
                 const float* __restrict__ Hf,
                 const float* __restrict__ HL,
                 float* v0, float* pA, float* pB,
                 float* __restrict__ out)
{
    // LDS overlays: chain: vsum[64][132] (33792 B) + enc[32][132] (16896 B)
    //               init:  enc[32][129] (16512 B)
    //               final: hl[64][129] (33024 B) + vs[64][33] (8448 B)
    __shared__ __align__(16) unsigned char smem[50688];
    const int tid = threadIdx.x;
    const int bid = blockIdx.x;

    // ---- phase 0: init v0[p][b] (all 256 blocks, 32 b each) ----
    {
        float* encs = (float*)smem;        // [32][129]
        const int b0i = bid * 32;
        {
            const int bL = tid >> 4, ec = (tid & 15) * 8;
            const __half* er = encH + ((size_t)(b0i + bL) * 12 + 0) * 128 + ec;
            uint4 u = *(const uint4*)er;
            const __half* hp = (const __half*)&u;
            #pragma unroll
            for (int j = 0; j < 8; ++j)
                encs[bL * 129 + ec + j] = __half2float(hp[j]);
        }
        __syncthreads();
        const int wvi = tid >> 6, lanei = tid & 63;
        const int bloc = lanei & 31, ph = lanei >> 5;
        const int p0 = wvi * 8 + ph * 4;
        const int b = b0i + bloc;
        float a0 = 0, a1 = 0, a2 = 0, a3 = 0;
        for (int e = 0; e < 128; ++e) {
            const float ev = encs[bloc * 129 + e];
            const float4 h = *(const float4*)&Hf[e * 64 + p0];  // half-wave-uniform
            a0 += ev * h.x; a1 += ev * h.y; a2 += ev * h.z; a3 += ev * h.w;
        }
        v0[(size_t)(p0 + 0) * B_ALL + b] = a0;
        v0[(size_t)(p0 + 1) * B_ALL + b] = a1;
        v0[(size_t)(p0 + 2) * B_ALL + b] = a2;
        v0[(size_t)(p0 + 3) * B_ALL + b] = a3;
    }
    grid_sync_fused();

    // ---- phases 1..10: chain ----
    const int b0 = (bid & 63) * 128;
    const int egp = bid >> 6;           // 0..3
    const int wv = tid >> 6, lane = tid & 63;
    const int l32 = lane & 31, half = lane >> 5;
    const int eh = wv >> 2, mf = (wv >> 1) & 1, bh = wv & 1;

    float* vsum  = (float*)smem;               // [64][132]
    float* encs2 = (float*)(smem + 33792);     // [32][132]

    const float* vIn = v0;
    float* vOut = pA;
    const unsigned short* Hsh = HmH;
    const unsigned short* Hsl = HmL;

    #pragma unroll 1
    for (int t = 1; t <= 10; ++t) {
        // stage vsum = sum of partials (64p x 128b), 512 threads
        if (t == 1) {
            #pragma unroll
            for (int k = 0; k < 4; ++k) {
                const int p  = (tid >> 5) + k * 16;
                const int bl = (tid & 31) * 4;
                *(float4*)&vsum[p * 132 + bl] =
                    *(const float4*)&vIn[(size_t)p * B_ALL + b0 + bl];
            }
        } else {
            #pragma unroll
            for (int k = 0; k < 4; ++k) {
                const int p  = (tid >> 5) + k * 16;
                const int bl = (tid & 31) * 4;
                float4 s = {0.f, 0.f, 0.f, 0.f};
                #pragma unroll
                for (int g = 0; g < 4; ++g) {
                    const float4 u = *(const float4*)&vIn[(size_t)g * 524288
                                                          + (size_t)p * B_ALL + b0 + bl];
                    s.x += u.x; s.y += u.y; s.z += u.z; s.w += u.w;
                }
                *(float4*)&vsum[p * 132 + bl] = s;
            }
        }
        // stage enc slice [32 e][128 b]
        {
            const int bL = tid & 127, eq = tid >> 7;   // eq 0..3
            const __half* er = encH + ((size_t)(b0 + bL) * 12 + t) * 128
                               + egp * 32 + eq * 8;
            uint4 u = *(const uint4*)er;
            const __half* hp = (const __half*)&u;
            #pragma unroll
            for (int el = 0; el < 8; ++el)
                encs2[(eq * 8 + el) * 132 + bL] = __half2float(hp[el]);
        }
        __syncthreads();

        // B-frags: v hi/lo split from LDS (held in registers)
        bfrag vbh_[2][4], vbl_[2][4];
        #pragma unroll
        for (int nf = 0; nf < 2; ++nf) {
            const int bcol = bh * 64 + nf * 32 + l32;
            #pragma unroll
            for (int s = 0; s < 4; ++s) {
                const int p0 = s * 16 + half * 8;
                bfrag hb, lb;
                #pragma unroll
                for (int j = 0; j < 8; ++j) {
                    const float f = vsum[(p0 + j) * 132 + bcol];
                    const unsigned short hi = bf16_rne(f);
                    const unsigned short lo = bf16_rne(f - bf16_f32(hi));
                    hb[j] = (short)hi;
                    lb[j] = (short)lo;
                }
                vbh_[nf][s] = hb;
                vbl_[nf][s] = lb;
            }
        }

        ffrag z = 0.0f;
        ffrag vn0 = 0.0f, vn1 = 0.0f;
        const int eb = eh * 16;   // local e-offset within block's 32 e

        #pragma unroll 2
        for (int e = 0; e < 16; ++e) {
            const float ev0 = encs2[(eb + e) * 132 + bh * 64 + l32];
            const float ev1 = encs2[(eb + e) * 132 + bh * 64 + 32 + l32];
            const unsigned short* hbase = Hsh + (size_t)(egp * 32 + eb + e) * 4096;
            const unsigned short* lbase = Hsl + (size_t)(egp * 32 + eb + e) * 4096;
            ffrag wa = z, wb = z;
            #pragma unroll
            for (int s = 0; s < 4; ++s) {
                const int fo = (((mf * 4 + s) * 2 + half) * 32 + l32) * 8;
                const bfrag ah = *(const bfrag*)(hbase + fo);
                const bfrag al = *(const bfrag*)(lbase + fo);
                wa = __builtin_amdgcn_mfma_f32_32x32x16_bf16(ah, vbh_[0][s], wa, 0, 0, 0);
                wa = __builtin_amdgcn_mfma_f32_32x32x16_bf16(ah, vbl_[0][s], wa, 0, 0, 0);
                wa = __builtin_amdgcn_mfma_f32_32x32x16_bf16(al, vbh_[0][s], wa, 0, 0, 0);
                wb = __builtin_amdgcn_mfma_f32_32x32x16_bf16(ah, vbh_[1][s], wb, 0, 0, 0);
                wb = __builtin_amdgcn_mfma_f32_32x32x16_bf16(ah, vbl_[1][s], wb, 0, 0, 0);
                wb = __builtin_amdgcn_mfma_f32_32x32x16_bf16(al, vbh_[1][s], wb, 0, 0, 0);
            }
            vn0 += wa * ev0;
            vn1 += wb * ev1;
        }

        // cross-eh combine in LDS (vsum region is dead now), then eh0 writes
        __syncthreads();   // all waves done reading vsum/encs2
        float4* sc = (float4*)vsum;
        if (eh == 1) {
            #pragma unroll
            for (int nf = 0; nf < 2; ++nf) {
                const ffrag vv = nf ? vn1 : vn0;
                const int slot = (mf * 2 + bh) * 2 + nf;
                #pragma unroll
                for (int q = 0; q < 4; ++q) {
                    float4 f4 = {vv[q * 4 + 0], vv[q * 4 + 1],
                                 vv[q * 4 + 2], vv[q * 4 + 3]};
                    sc[(slot * 4 + q) * 64 + lane] = f4;
                }
            }
        }
        __syncthreads();
        if (eh == 0) {
            #pragma unroll
            for (int nf = 0; nf < 2; ++nf) {
                ffrag vv = nf ? vn1 : vn0;
                const int slot = (mf * 2 + bh) * 2 + nf;
                #pragma unroll
                for (int q = 0; q < 4; ++q) {
                    const float4 f4 = sc[(slot * 4 + q) * 64 + lane];
                    vv[q * 4 + 0] += f4.x; vv[q * 4 + 1] += f4.y;
                    vv[q * 4 + 2] += f4.z; vv[q * 4 + 3] += f4.w;
                }
                const int b = b0 + bh * 64 + nf * 32 + l32;
                #pragma unroll
                for (int i = 0; i < 16; ++i) {
                    const int r = mf * 32 + (i & 3) + 8 * (i >> 2) + 4 * half;
                    vOut[(size_t)egp * 524288 + (size_t)r * B_ALL + b] = vv[i];
                }
            }
        }

        grid_sync_fused();

        vIn = vOut;
        vOut = (t & 1) ? pB : pA;
        Hsh += 524288;
        Hsl += 524288;
    }

    // ---- final: 256 blocks, 32 b each; sum 4 partials in LDS ----
    {
        float* hl_s = (float*)smem;              // [64][129]
        float* vs   = (float*)(smem + 33024);    // [64][33]
        const float* vFin = pB;                  // t=10 wrote pB
        const int fb0 = bid * 32;
        #pragma unroll
        for (int i = 0; i < 16; ++i) {
            const int idx = i * 512 + tid;       // 8192 floats of HL
            hl_s[(idx >> 7) * 129 + (idx & 127)] = HL[idx];
        }
        {
            const int p  = tid >> 3;
            const int bs = (tid & 7) * 4;
            float4 s = {0.f, 0.f, 0.f, 0.f};
            #pragma unroll
            for (int g = 0; g < 4; ++g) {
                const float4 u = *(const float4*)&vFin[(size_t)g * 524288
                                                       + (size_t)p * B_ALL + fb0 + bs];
                s.x += u.x; s.y += u.y; s.z += u.z; s.w += u.w;
            }
            vs[p * 33 + bs + 0] = s.x;
            vs[p * 33 + bs + 1] = s.y;
            vs[p * 33 + bs + 2] = s.z;
            vs[p * 33 + bs + 3] = s.w;
        }
        __syncthreads();
        const int wv2 = tid >> 6, lane2 = tid & 63;
        #pragma unroll
        for (int q = 0; q < 4; ++q) {
            const int bl = wv2 * 4 + q;
            const __half* er = encH + ((size_t)(fb0 + bl) * 12 + 11) * 128;
            float L = 0.0f;
            #pragma unroll 16
            for (int e = 0; e < 128; ++e)
                L += __half2float(er[e]) * hl_s[lane2 * 129 + e];
            float pre = vs[lane2 * 33 + bl] * L;
            #pragma unroll
            for (int off = 32; off > 0; off >>= 1)
                pre += __shfl_down(pre, off);
            if (lane2 == 0) out[fb0 + bl] = pre;
        }
    }
}

extern "C" void kernel_launch(void* const* d_in, const int* in_sizes, int n_in,
                              void* d_out, int out_size, void* d_ws, size_t ws_size,
                              hipStream_t stream) {
    const float* x  = (const float*)d_in[0];
    const float* W1 = (const float*)d_in[1];
    const float* b1 = (const float*)d_in[2];
    const float* W2 = (const float*)d_in[3];
    const float* b2 = (const float*)d_in[4];
    const float* Hf = (const float*)d_in[5];
    const float* Hm = (const float*)d_in[6];
    const float* HL = (const float*)d_in[7];
    float* out = (float*)d_out;
    (void)in_sizes; (void)n_in; (void)out_size;

    char* ws = (char*)d_ws;
    __half* encH        = (__half*)(ws + O_ENC);
    unsigned short* HmH = (unsigned short*)(ws + O_HMH);
    unsigned short* HmL = (unsigned short*)(ws + O_HML);
    __half* w1f         = (__half*)(ws + O_W1F);
    __half* w2f         = (__half*)(ws + O_W2F);
    float* v0           = (float*)(ws + O_V0);
    float* vT           = (float*)(ws + O_V0);   // fallback alias

    const bool part = (ws_size >= NEED_PARTIAL);

    prep_kernel<<<dim3(5216), dim3(256), 0, stream>>>(W1, W2, Hm, w1f, w2f, HmH, HmL);
    enc_kernel<<<dim3(1536), dim3(256), 0, stream>>>(x, b1, b2, w1f, w2f, encH);

    if (part) {
        float* pA = (float*)(ws + O_PA);
        float* pB = (float*)(ws + O_PB);
        fused_chain<<<dim3(256), dim3(512), 0, stream>>>(
            HmH, HmL, encH, Hf, HL, v0, pA, pB, out);
    } else {
        init_kernel<<<dim3(128), dim3(256), 0, stream>>>(encH, Hf, v0);
        float* vA = (float*)(ws + O_VA);
        float* vB = (float*)(ws + O_VB);
        const float* cur = v0;
        for (int t = 1; t <= 10; ++t) {
            float* nxt = (t & 1) ? vA : vB;
            hipMemsetAsync(nxt, 0, (size_t)64 * B_ALL * sizeof(float), stream);
            chain_step<<<dim3(512), dim3(256), 0, stream>>>(
                HmH + (size_t)(t - 1) * 524288, HmL + (size_t)(t - 1) * 524288,
                encH, cur, 1, nxt, 0, t);
            cur = nxt;
        }
        reduce_t_kernel<<<dim3(128), dim3(256), 0, stream>>>(cur, 1, vT);
        final_kernel<<<dim3(512), dim3(64), 0, stream>>>(encH, HL, vT, out);
    }
}

// Round 3
// 1109.107 us; speedup vs baseline: 1.5625x; 1.0336x over previous
//
#include <hip/hip_runtime.h>
#include <hip/hip_fp16.h>

// Hankel MPS, round 8: persistent fused chain, fence-FREE sc1 data handoff.
//
// Round-7 post-mortem: per-barrier fence(release)=buffer_wbl2 and
// fence(acquire)=buffer_inv (x256 blocks x11 barriers) flushed/invalidated the
// whole per-XCD L2 every step -> 1.73 GB HBM traffic @1.65 TB/s = 1050us.
//
// Round-8: cross-block data (v0/pA/pB) accessed ONLY via agent-scope RELAXED
// atomics (sc1: bypasses non-coherent XCD L2, served by die-level Infinity
// Cache). No wbl2/inv anywhere:
//   release = __syncthreads' implicit vmcnt(0) drain (all sc1 stores at MALL)
//   acquire = none needed (sc1 loads cannot hit stale L2)
// g_bar-reset vs g_gen-bump ordered by one s_waitcnt vmcnt(0).
// L2 stays warm for H/encH across all 10 steps.
//
// ws layout unchanged (partial path 82.0 MB).

#define B_ALL 8192
#define TT    12

typedef short bfrag __attribute__((ext_vector_type(8)));      // 8 bf16
typedef _Float16 hfrag __attribute__((ext_vector_type(8)));   // 8 fp16
typedef float ffrag __attribute__((ext_vector_type(16)));     // 32x32 C/D

#define O_ENC   0ULL
#define O_HMH   25165824ULL
#define O_HML   35651584ULL
#define O_W1F   46137344ULL
#define O_W2F   46202880ULL
#define O_V0    46333952ULL            // 2 MB (v0; reused as vT in fallback)
#define O_PA    48431104ULL            // 16 MB reserved (4x2MB used)
#define O_PB    65208320ULL            // 16 MB reserved (4x2MB used)
#define NEED_PARTIAL 81985536ULL
#define O_VA    48431104ULL            // atomic path: 2 MB
#define O_VB    50528256ULL            // atomic path: 2 MB

__device__ __forceinline__ unsigned short bf16_rne(float f) {
    unsigned int u = __builtin_bit_cast(unsigned int, f);
    unsigned int r = (u + 0x7fffu + ((u >> 16) & 1u)) >> 16;
    return (unsigned short)r;
}
__device__ __forceinline__ float bf16_f32(unsigned short h) {
    unsigned int u = ((unsigned int)h) << 16;
    return __builtin_bit_cast(float, u);
}

// sc1 (device-coherent) accessors for cross-block partial buffers.
__device__ __forceinline__ void st_f1_sc1(float* p, float v) {
    __hip_atomic_store(p, v, __ATOMIC_RELAXED, __HIP_MEMORY_SCOPE_AGENT);
}
__device__ __forceinline__ float2 ld_f2_sc1(const float* p) {
    unsigned long long u = __hip_atomic_load((unsigned long long*)(size_t)p,
                                             __ATOMIC_RELAXED,
                                             __HIP_MEMORY_SCOPE_AGENT);
    return __builtin_bit_cast(float2, u);
}

// ---------------- prep (unchanged) ----------------
__global__ __launch_bounds__(256)
void prep_kernel(const float* __restrict__ W1, const float* __restrict__ W2,
                 const float* __restrict__ Hm,
                 __half* __restrict__ w1f, __half* __restrict__ w2f,
                 unsigned short* __restrict__ Hh, unsigned short* __restrict__ Hl)
{
    const long long N_W1 = 32768, N_W2 = 65536, N_H = 10LL * 128 * 4096;
    const long long total = N_W1 + N_W2 + N_H;
    const long long stride = (long long)gridDim.x * blockDim.x;
    for (long long idx = (long long)blockIdx.x * blockDim.x + threadIdx.x;
         idx < total; idx += stride) {
        if (idx < N_W1) {
            const int w = (int)idx;
            const int jn = w >> 11, ks = (w >> 9) & 3, half = (w >> 8) & 1;
            const int jl = (w >> 3) & 31, jj = w & 7;
            const int j = jn * 32 + jl, d = ks * 16 + half * 8 + jj;
            w1f[w] = __float2half(W1[j * 64 + d]);
        } else if (idx < N_W1 + N_W2) {
            const int w = (int)(idx - N_W1);
            const int en = w >> 14, ks2g = (w >> 9) & 31, half = (w >> 8) & 1;
            const int el = (w >> 3) & 31, jj = w & 7;
            const int e = en * 32 + el, j = ks2g * 16 + half * 8 + jj;
            w2f[w] = __float2half(W2[e * 512 + j]);
        } else {
            const long long q = idx - N_W1 - N_W2;
            const int t = (int)(q / 524288);
            const int rem = (int)(q % 524288);
            const int e = rem >> 12;
            const int f = rem & 4095;
            const int mf = f >> 11, s = (f >> 9) & 3, half = (f >> 8) & 1;
            const int l = (f >> 3) & 31, j = f & 7;
            const int p = s * 16 + half * 8 + j;
            const int r = mf * 32 + l;
            const float val = Hm[(((long long)t * 64 + p) * 128 + e) * 64 + r];
            const unsigned short hi = bf16_rne(val);
            const unsigned short lo = bf16_rne(val - bf16_f32(hi));
            Hh[q] = hi;
            Hl[q] = lo;
        }
    }
}

// ---------------- encoder (unchanged) ----------------
__global__ __launch_bounds__(256)
void enc_kernel(const float* __restrict__ x,
                const float* __restrict__ b1, const float* __restrict__ b2,
                const __half* __restrict__ w1f, const __half* __restrict__ w2f,
                __half* __restrict__ encH)
{
    __shared__ __align__(16) unsigned char smem[17408];
    float* x_s  = (float*)smem;
    __half* h_s = (__half*)smem;

    const int tid   = threadIdx.x;
    const int wv    = tid >> 6;
    const int lane  = tid & 63;
    const int l32   = lane & 31;
    const int half  = lane >> 5;
    const int msub  = wv >> 1;
    const int nhalf = wv & 1;
    const int m0    = blockIdx.x * 64;

    #pragma unroll
    for (int i = 0; i < 4; ++i) {
        const int f4 = i * 256 + tid;
        const int r = f4 >> 4, c4 = (f4 & 15) * 4;
        *(float4*)&x_s[r * 68 + c4] =
            *(const float4*)&x[(long long)(m0 + r) * 64 + c4];
    }
    __syncthreads();

    hfrag xa[4];
    #pragma unroll
    for (int ks = 0; ks < 4; ++ks) {
        const float* src = &x_s[(msub * 32 + l32) * 68 + ks * 16 + half * 8];
        const float4 a = *(const float4*)src;
        const float4 b = *(const float4*)(src + 4);
        hfrag v;
        v[0] = (_Float16)a.x; v[1] = (_Float16)a.y;
        v[2] = (_Float16)a.z; v[3] = (_Float16)a.w;
        v[4] = (_Float16)b.x; v[5] = (_Float16)b.y;
        v[6] = (_Float16)b.z; v[7] = (_Float16)b.w;
        xa[ks] = v;
    }
    __syncthreads();

    ffrag c2[2];
    c2[0] = 0.0f; c2[1] = 0.0f;

    for (int chunk = 0; chunk < 4; ++chunk) {
        ffrag c1[2];
        float b1j[2];
        #pragma unroll
        for (int nf = 0; nf < 2; ++nf) {
            const int jn = chunk * 4 + nhalf * 2 + nf;
            b1j[nf] = b1[jn * 32 + l32];
            ffrag acc = 0.0f;
            #pragma unroll
            for (int ks = 0; ks < 4; ++ks) {
                const hfrag bh = *(const hfrag*)(w1f + (jn * 4 + ks) * 512
                                                 + half * 256 + l32 * 8);
                acc = __builtin_amdgcn_mfma_f32_32x32x16_f16(xa[ks], bh, acc, 0, 0, 0);
            }
            c1[nf] = acc;
        }
        __syncthreads();
        #pragma unroll
        for (int nf = 0; nf < 2; ++nf) {
            #pragma unroll
            for (int i2 = 0; i2 < 16; ++i2) {
                const int m_row = (i2 & 3) + 8 * (i2 >> 2) + 4 * half;
                const float v = fmaxf(c1[nf][i2] + b1j[nf], 0.0f);
                h_s[(msub * 32 + m_row) * 136 + nhalf * 64 + nf * 32 + l32] =
                    __float2half(v);
            }
        }
        __syncthreads();
        #pragma unroll
        for (int ks2 = 0; ks2 < 8; ++ks2) {
            const hfrag a = *(const hfrag*)&h_s[(msub * 32 + l32) * 136
                                                + ks2 * 16 + half * 8];
            const int ks2g = chunk * 8 + ks2;
            #pragma unroll
            for (int ef = 0; ef < 2; ++ef) {
                const int en = nhalf * 2 + ef;
                const hfrag b = *(const hfrag*)(w2f + (en * 32 + ks2g) * 512
                                                + half * 256 + l32 * 8);
                c2[ef] = __builtin_amdgcn_mfma_f32_32x32x16_f16(a, b, c2[ef], 0, 0, 0);
            }
        }
    }

    #pragma unroll
    for (int ef = 0; ef < 2; ++ef) {
        const int e = nhalf * 64 + ef * 32 + l32;
        const float b2e = b2[e];
        #pragma unroll
        for (int i2 = 0; i2 < 16; ++i2) {
            const int m_row = (i2 & 3) + 8 * (i2 >> 2) + 4 * half;
            const int m_g = m0 + msub * 32 + m_row;
            encH[(long long)m_g * 128 + e] =
                __float2half(fmaxf(c2[ef][i2] + b2e, 0.0f));
        }
    }
}

// ---------------- init (fallback path) ----------------
__global__ __launch_bounds__(256, 2)
void init_kernel(const __half* __restrict__ encH, const float* __restrict__ Hf,
                 float* __restrict__ vOut)   // [64][8192]
{
    __shared__ float enc_s[64 * 129];   // [b][e]
    const int tid = threadIdx.x;
    const int b0 = blockIdx.x * 64;     // grid 128
    {
        const int b = tid >> 2, ec = (tid & 3) * 32;
        const __half* er = encH + ((size_t)(b0 + b) * 12 + 0) * 128 + ec;
        #pragma unroll
        for (int q = 0; q < 4; ++q) {
            uint4 u = *(const uint4*)(er + q * 8);
            const __half* hp = (const __half*)&u;
            #pragma unroll
            for (int j = 0; j < 8; ++j)
                enc_s[b * 129 + ec + q * 8 + j] = __half2float(hp[j]);
        }
    }
    __syncthreads();
    const int wv = tid >> 6, lane = tid & 63;
    const int b = b0 + lane;
    for (int pc = 0; pc < 16; pc += 4) {
        const int p = wv * 16 + pc;
        float a0 = 0, a1 = 0, a2 = 0, a3 = 0;
        for (int e = 0; e < 128; ++e) {
            const float ev = enc_s[lane * 129 + e];
            const float4 h = *(const float4*)&Hf[e * 64 + p];   // wave-uniform
            a0 += ev * h.x; a1 += ev * h.y; a2 += ev * h.z; a3 += ev * h.w;
        }
        vOut[(size_t)(p + 0) * B_ALL + b] = a0;
        vOut[(size_t)(p + 1) * B_ALL + b] = a1;
        vOut[(size_t)(p + 2) * B_ALL + b] = a2;
        vOut[(size_t)(p + 3) * B_ALL + b] = a3;
    }
}

// ---------------- chain step (fallback path, unchanged) ----------------
__global__ __launch_bounds__(256, 2)
void chain_step(const unsigned short* __restrict__ Hsh,  // this t: [128e][4096]
                const unsigned short* __restrict__ Hsl,
                const __half* __restrict__ encH,
                const float* __restrict__ vIn, int nIn,   // nIn partials [p][b]
                float* __restrict__ vOut, int partStride, // 0 => atomicAdd flat
                int t)
{
    __shared__ float vsum[64 * 132];    // [p][b0..b0+127]
    __shared__ float enc_s[16 * 132];   // [e][b]

    const int tid = threadIdx.x;
    const int b0 = (blockIdx.x & 63) * 128;
    const int eg = blockIdx.x >> 6;
    const int e0 = eg * 16;

    #pragma unroll
    for (int k = 0; k < 8; ++k) {
        const int p  = (tid >> 5) + k * 8;
        const int bl = (tid & 31) * 4;
        float4 s = {0.f, 0.f, 0.f, 0.f};
        for (int g = 0; g < nIn; ++g) {
            const float4 u = *(const float4*)&vIn[(size_t)g * 524288
                                                  + (size_t)p * B_ALL + b0 + bl];
            s.x += u.x; s.y += u.y; s.z += u.z; s.w += u.w;
        }
        *(float4*)&vsum[p * 132 + bl] = s;
    }
    if (tid < 128) {
        const __half* er = encH + ((size_t)(b0 + tid) * 12 + t) * 128 + e0;
        uint4 u0 = *(const uint4*)er;
        uint4 u1 = *(const uint4*)(er + 8);
        const __half* h0 = (const __half*)&u0;
        const __half* h1 = (const __half*)&u1;
        #pragma unroll
        for (int el = 0; el < 8; ++el) enc_s[el * 132 + tid] = __half2float(h0[el]);
        #pragma unroll
        for (int el = 0; el < 8; ++el) enc_s[(el + 8) * 132 + tid] = __half2float(h1[el]);
    }
    __syncthreads();

    const int wv = tid >> 6, lane = tid & 63;
    const int l32 = lane & 31, half = lane >> 5;
    const int mf = wv >> 1, bh = wv & 1;

    bfrag vbh_[2][4], vbl_[2][4];
    #pragma unroll
    for (int nf = 0; nf < 2; ++nf) {
        const int bcol = bh * 64 + nf * 32 + l32;
        #pragma unroll
        for (int s = 0; s < 4; ++s) {
            const int p0 = s * 16 + half * 8;
            bfrag hb, lb;
            #pragma unroll
            for (int j = 0; j < 8; ++j) {
                const float f = vsum[(p0 + j) * 132 + bcol];
                const unsigned short hi = bf16_rne(f);
                const unsigned short lo = bf16_rne(f - bf16_f32(hi));
                hb[j] = (short)hi;
                lb[j] = (short)lo;
            }
            vbh_[nf][s] = hb;
            vbl_[nf][s] = lb;
        }
    }

    ffrag z = 0.0f;
    ffrag vn0 = 0.0f, vn1 = 0.0f;

    #pragma unroll 2
    for (int e = 0; e < 16; ++e) {
        const float ev0 = enc_s[e * 132 + bh * 64 + l32];
        const float ev1 = enc_s[e * 132 + bh * 64 + 32 + l32];
        const unsigned short* hbase = Hsh + (size_t)(e0 + e) * 4096;
        const unsigned short* lbase = Hsl + (size_t)(e0 + e) * 4096;
        ffrag wa = z, wb = z;
        #pragma unroll
        for (int s = 0; s < 4; ++s) {
            const int fo = (((mf * 4 + s) * 2 + half) * 32 + l32) * 8;
            const bfrag ah = *(const bfrag*)(hbase + fo);
            const bfrag al = *(const bfrag*)(lbase + fo);
            wa = __builtin_amdgcn_mfma_f32_32x32x16_bf16(ah, vbh_[0][s], wa, 0, 0, 0);
            wa = __builtin_amdgcn_mfma_f32_32x32x16_bf16(ah, vbl_[0][s], wa, 0, 0, 0);
            wa = __builtin_amdgcn_mfma_f32_32x32x16_bf16(al, vbh_[0][s], wa, 0, 0, 0);
            wb = __builtin_amdgcn_mfma_f32_32x32x16_bf16(ah, vbh_[1][s], wb, 0, 0, 0);
            wb = __builtin_amdgcn_mfma_f32_32x32x16_bf16(ah, vbl_[1][s], wb, 0, 0, 0);
            wb = __builtin_amdgcn_mfma_f32_32x32x16_bf16(al, vbh_[1][s], wb, 0, 0, 0);
        }
        vn0 += wa * ev0;
        vn1 += wb * ev1;
    }

    #pragma unroll
    for (int nf = 0; nf < 2; ++nf) {
        const ffrag vv = nf ? vn1 : vn0;
        const int b = b0 + bh * 64 + nf * 32 + l32;
        #pragma unroll
        for (int i = 0; i < 16; ++i) {
            const int r = mf * 32 + (i & 3) + 8 * (i >> 2) + 4 * half;
            if (partStride)
                vOut[(size_t)eg * partStride + (size_t)r * B_ALL + b] = vv[i];
            else
                atomicAdd(&vOut[(size_t)r * B_ALL + b], vv[i]);
        }
    }
}

// ---------------- reduce + transpose (fallback path) ----------------
__global__ __launch_bounds__(256)
void reduce_t_kernel(const float* __restrict__ vIn, int nIn,
                     float* __restrict__ vT)   // [8192][64]
{
    __shared__ float vt[64][68];
    const int tid = threadIdx.x;
    const int b0 = blockIdx.x * 64;   // grid 128
    #pragma unroll
    for (int k = 0; k < 8; ++k) {
        const int p  = (tid >> 5) + k * 8;
        const int bl = (tid & 31) * 2;
        float2 s = {0.f, 0.f};
        for (int g = 0; g < nIn; ++g) {
            const float2 u = *(const float2*)&vIn[(size_t)g * 524288
                                                  + (size_t)p * B_ALL + b0 + bl];
            s.x += u.x; s.y += u.y;
        }
        vt[bl][p] = s.x;
        vt[bl + 1][p] = s.y;
    }
    __syncthreads();
    const int b = tid >> 2, c = (tid & 3) * 16;
    float4* dst = (float4*)&vT[(size_t)(b0 + b) * 64 + c];
    #pragma unroll
    for (int q = 0; q < 4; ++q)
        dst[q] = *(float4*)&vt[b][c + q * 4];
}

// ---------------- final (fallback path) ----------------
__global__ __launch_bounds__(64)
void final_kernel(const __half* __restrict__ encH, const float* __restrict__ HL,
                  const float* __restrict__ vT, float* __restrict__ out)
{
    __shared__ float hl_s[64 * 129];
    const int tid = threadIdx.x;
    const int b0 = blockIdx.x * 16;
    for (int i = 0; i < 128; ++i) {
        const int idx = i * 64 + tid;
        hl_s[(idx >> 7) * 129 + (idx & 127)] = HL[idx];
    }
    __syncthreads();
    const int p = tid;
    for (int bs = 0; bs < 16; ++bs) {
        const int b = b0 + bs;
        const __half* er = encH + (size_t)(b * 12 + 11) * 128;
        float L = 0.0f;
        #pragma unroll 16
        for (int e = 0; e < 128; ++e)
            L += __half2float(er[e]) * hl_s[p * 129 + e];
        float pre = vT[(size_t)b * 64 + p] * L;
        #pragma unroll
        for (int off = 32; off > 0; off >>= 1)
            pre += __shfl_down(pre, off);
        if (tid == 0) out[b] = pre;
    }
}

// ---------------- persistent fused chain ----------------
// Fence-free sense-reversal grid barrier:
//  - all cross-block data moves via sc1 (agent-scope relaxed atomics)
//  - release: __syncthreads drains vmcnt(0) (sc1 stores at coherence point)
//  - acquire: nothing (sc1 loads bypass the non-coherent XCD L2)
//  - g_bar reset ordered before g_gen bump via s_waitcnt vmcnt(0)
#define NB_FUSED 256

__device__ unsigned int g_bar = 0u;
__device__ unsigned int g_gen = 0u;

__device__ __forceinline__ void grid_sync_fused() {
    __syncthreads();   // drains vmcnt(0): all waves' sc1 stores completed
    if (threadIdx.x == 0) {
        const unsigned g =
            __hip_atomic_load(&g_gen, __ATOMIC_RELAXED, __HIP_MEMORY_SCOPE_AGENT);
        const unsigned a =
            __hip_atomic_fetch_add(&g_bar, 1u, __ATOMIC_RELAXED,
                                   __HIP_MEMORY_SCOPE_AGENT);
        if (a == NB_FUSED - 1u) {
            __hip_atomic_store(&g_bar, 0u, __ATOMIC_RELAXED,
                               __HIP_MEMORY_SCOPE_AGENT);
            asm volatile("s_waitcnt vmcnt(0)" ::: "memory");  // reset lands first
            __hip_atomic_store(&g_gen, g + 1u, __ATOMIC_RELAXED,
                               __HIP_MEMORY_SCOPE_AGENT);
        } else {
            while (__hip_atomic_load(&g_gen, __ATOMIC_RELAXED,
                                     __HIP_MEMORY_SCOPE_AGENT) == g)
                __builtin_amdgcn_s_sleep(4);
        }
    }
    __syncthreads();
}

// 256 blocks x 512 threads (8 waves). Block = (btile: 128 b) x (egp: 32 e).
// Waves: eh = wv>>2 (16-e half), mf = (wv>>1)&1 (r half), bh = wv&1 (b half).
// 4 partials (egp 0..3), stride 524288 floats each.
__global__ __launch_bounds__(512, 4)
void fused_chain(const unsigned short* __restrict__ HmH,
                 const unsigned short* __restrict__ HmL,
                 const __half* __restrict__ encH,
                 const float* __restrict__ Hf,
                 const float* __restrict__ HL,
                 float* v0, float* pA, float* pB,
                 float* __restrict__ out)
{
    // LDS overlays: chain: vsum[64][132] (33792 B) + enc[32][132] (16896 B)
    //               init:  enc[32][129] (16512 B)
    //               final: hl[64][129] (33024 B) + vs[64][33] (8448 B)
    __shared__ __align__(16) unsigned char smem[50688];
    const int tid = threadIdx.x;
    const int bid = blockIdx.x;

    // ---- phase 0: init v0[p][b] (all 256 blocks, 32 b each) ----
    {
        float* encs = (float*)smem;        // [32][129]
        const int b0i = bid * 32;
        {
            const int bL = tid >> 4, ec = (tid & 15) * 8;
            const __half* er = encH + ((size_t)(b0i + bL) * 12 + 0) * 128 + ec;
            uint4 u = *(const uint4*)er;
            const __half* hp = (const __half*)&u;
            #pragma unroll
            for (int j = 0; j < 8; ++j)
                encs[bL * 129 + ec + j] = __half2float(hp[j]);
        }
        __syncthreads();
        const int wvi = tid >> 6, lanei = tid & 63;
        const int bloc = lanei & 31, ph = lanei >> 5;
        const int p0 = wvi * 8 + ph * 4;
        const int b = b0i + bloc;
        float a0 = 0, a1 = 0, a2 = 0, a3 = 0;
        for (int e = 0; e < 128; ++e) {
            const float ev = encs[bloc * 129 + e];
            const float4 h = *(const float4*)&Hf[e * 64 + p0];  // half-wave-uniform
            a0 += ev * h.x; a1 += ev * h.y; a2 += ev * h.z; a3 += ev * h.w;
        }
        st_f1_sc1(&v0[(size_t)(p0 + 0) * B_ALL + b], a0);
        st_f1_sc1(&v0[(size_t)(p0 + 1) * B_ALL + b], a1);
        st_f1_sc1(&v0[(size_t)(p0 + 2) * B_ALL + b], a2);
        st_f1_sc1(&v0[(size_t)(p0 + 3) * B_ALL + b], a3);
    }
    grid_sync_fused();

    // ---- phases 1..10: chain ----
    const int b0 = (bid & 63) * 128;
    const int egp = bid >> 6;           // 0..3
    const int wv = tid >> 6, lane = tid & 63;
    const int l32 = lane & 31, half = lane >> 5;
    const int eh = wv >> 2, mf = (wv >> 1) & 1, bh = wv & 1;

    float* vsum  = (float*)smem;               // [64][132]
    float* encs2 = (float*)(smem + 33792);     // [32][132]

    const float* vIn = v0;
    float* vOut = pA;
    const unsigned short* Hsh = HmH;
    const unsigned short* Hsl = HmL;

    #pragma unroll 1
    for (int t = 1; t <= 10; ++t) {
        // stage vsum = sum of partials (64p x 128b), 512 threads, sc1 loads
        if (t == 1) {
            #pragma unroll
            for (int k = 0; k < 4; ++k) {
                const int p  = (tid >> 5) + k * 16;
                const int bl = (tid & 31) * 4;
                const float* base = &vIn[(size_t)p * B_ALL + b0 + bl];
                const float2 u0 = ld_f2_sc1(base);
                const float2 u1 = ld_f2_sc1(base + 2);
                *(float2*)&vsum[p * 132 + bl]     = u0;
                *(float2*)&vsum[p * 132 + bl + 2] = u1;
            }
        } else {
            #pragma unroll
            for (int k = 0; k < 4; ++k) {
                const int p  = (tid >> 5) + k * 16;
                const int bl = (tid & 31) * 4;
                float2 s01 = {0.f, 0.f}, s23 = {0.f, 0.f};
                #pragma unroll
                for (int g = 0; g < 4; ++g) {
                    const float* base = &vIn[(size_t)g * 524288
                                             + (size_t)p * B_ALL + b0 + bl];
                    const float2 u0 = ld_f2_sc1(base);
                    const float2 u1 = ld_f2_sc1(base + 2);
                    s01.x += u0.x; s01.y += u0.y;
                    s23.x += u1.x; s23.y += u1.y;
                }
                *(float2*)&vsum[p * 132 + bl]     = s01;
                *(float2*)&vsum[p * 132 + bl + 2] = s23;
            }
        }
        // stage enc slice [32 e][128 b]
        {
            const int bL = tid & 127, eq = tid >> 7;   // eq 0..3
            const __half* er = encH + ((size_t)(b0 + bL) * 12 + t) * 128
                               + egp * 32 + eq * 8;
            uint4 u = *(const uint4*)er;
            const __half* hp = (const __half*)&u;
            #pragma unroll
            for (int el = 0; el < 8; ++el)
                encs2[(eq * 8 + el) * 132 + bL] = __half2float(hp[el]);
        }
        __syncthreads();

        // B-frags: v hi/lo split from LDS (held in registers)
        bfrag vbh_[2][4], vbl_[2][4];
        #pragma unroll
        for (int nf = 0; nf < 2; ++nf) {
            const int bcol = bh * 64 + nf * 32 + l32;
            #pragma unroll
            for (int s = 0; s < 4; ++s) {
                const int p0 = s * 16 + half * 8;
                bfrag hb, lb;
                #pragma unroll
                for (int j = 0; j < 8; ++j) {
                    const float f = vsum[(p0 + j) * 132 + bcol];
                    const unsigned short hi = bf16_rne(f);
                    const unsigned short lo = bf16_rne(f - bf16_f32(hi));
                    hb[j] = (short)hi;
                    lb[j] = (short)lo;
                }
                vbh_[nf][s] = hb;
                vbl_[nf][s] = lb;
            }
        }

        ffrag z = 0.0f;
        ffrag vn0 = 0.0f, vn1 = 0.0f;
        const int eb = eh * 16;   // local e-offset within block's 32 e

        #pragma unroll 2
        for (int e = 0; e < 16; ++e) {
            const float ev0 = encs2[(eb + e) * 132 + bh * 64 + l32];
            const float ev1 = encs2[(eb + e) * 132 + bh * 64 + 32 + l32];
            const unsigned short* hbase = Hsh + (size_t)(egp * 32 + eb + e) * 4096;
            const unsigned short* lbase = Hsl + (size_t)(egp * 32 + eb + e) * 4096;
            ffrag wa = z, wb = z;
            #pragma unroll
            for (int s = 0; s < 4; ++s) {
                const int fo = (((mf * 4 + s) * 2 + half) * 32 + l32) * 8;
                const bfrag ah = *(const bfrag*)(hbase + fo);
                const bfrag al = *(const bfrag*)(lbase + fo);
                wa = __builtin_amdgcn_mfma_f32_32x32x16_bf16(ah, vbh_[0][s], wa, 0, 0, 0);
                wa = __builtin_amdgcn_mfma_f32_32x32x16_bf16(ah, vbl_[0][s], wa, 0, 0, 0);
                wa = __builtin_amdgcn_mfma_f32_32x32x16_bf16(al, vbh_[0][s], wa, 0, 0, 0);
                wb = __builtin_amdgcn_mfma_f32_32x32x16_bf16(ah, vbh_[1][s], wb, 0, 0, 0);
                wb = __builtin_amdgcn_mfma_f32_32x32x16_bf16(ah, vbl_[1][s], wb, 0, 0, 0);
                wb = __builtin_amdgcn_mfma_f32_32x32x16_bf16(al, vbh_[1][s], wb, 0, 0, 0);
            }
            vn0 += wa * ev0;
            vn1 += wb * ev1;
        }

        // cross-eh combine in LDS (vsum region is dead now), then eh0 writes
        __syncthreads();   // all waves done reading vsum/encs2
        float4* sc = (float4*)vsum;
        if (eh == 1) {
            #pragma unroll
            for (int nf = 0; nf < 2; ++nf) {
                const ffrag vv = nf ? vn1 : vn0;
                const int slot = (mf * 2 + bh) * 2 + nf;
                #pragma unroll
                for (int q = 0; q < 4; ++q) {
                    float4 f4 = {vv[q * 4 + 0], vv[q * 4 + 1],
                                 vv[q * 4 + 2], vv[q * 4 + 3]};
                    sc[(slot * 4 + q) * 64 + lane] = f4;
                }
            }
        }
        __syncthreads();
        if (eh == 0) {
            #pragma unroll
            for (int nf = 0; nf < 2; ++nf) {
                ffrag vv = nf ? vn1 : vn0;
                const int slot = (mf * 2 + bh) * 2 + nf;
                #pragma unroll
                for (int q = 0; q < 4; ++q) {
                    const float4 f4 = sc[(slot * 4 + q) * 64 + lane];
                    vv[q * 4 + 0] += f4.x; vv[q * 4 + 1] += f4.y;
                    vv[q * 4 + 2] += f4.z; vv[q * 4 + 3] += f4.w;
                }
                const int b = b0 + bh * 64 + nf * 32 + l32;
                #pragma unroll
                for (int i = 0; i < 16; ++i) {
                    const int r = mf * 32 + (i & 3) + 8 * (i >> 2) + 4 * half;
                    st_f1_sc1(&vOut[(size_t)egp * 524288 + (size_t)r * B_ALL + b],
                              vv[i]);
                }
            }
        }

        grid_sync_fused();

        vIn = vOut;
        vOut = (t & 1) ? pB : pA;
        Hsh += 524288;
        Hsl += 524288;
    }

    // ---- final: 256 blocks, 32 b each; sum 4 partials in LDS ----
    {
        float* hl_s = (float*)smem;              // [64][129]
        float* vs   = (float*)(smem + 33024);    // [64][33]
        const float* vFin = pB;                  // t=10 wrote pB
        const int fb0 = bid * 32;
        #pragma unroll
        for (int i = 0; i < 16; ++i) {
            const int idx = i * 512 + tid;       // 8192 floats of HL
            hl_s[(idx >> 7) * 129 + (idx & 127)] = HL[idx];
        }
        {
            const int p  = tid >> 3;
            const int bs = (tid & 7) * 4;
            float4 s = {0.f, 0.f, 0.f, 0.f};
            #pragma unroll
            for (int g = 0; g < 4; ++g) {
                const float* base = &vFin[(size_t)g * 524288
                                          + (size_t)p * B_ALL + fb0 + bs];
                const float2 u0 = ld_f2_sc1(base);
                const float2 u1 = ld_f2_sc1(base + 2);
                s.x += u0.x; s.y += u0.y; s.z += u1.x; s.w += u1.y;
            }
            vs[p * 33 + bs + 0] = s.x;
            vs[p * 33 + bs + 1] = s.y;
            vs[p * 33 + bs + 2] = s.z;
            vs[p * 33 + bs + 3] = s.w;
        }
        __syncthreads();
        const int wv2 = tid >> 6, lane2 = tid & 63;
        #pragma unroll
        for (int q = 0; q < 4; ++q) {
            const int bl = wv2 * 4 + q;
            const __half* er = encH + ((size_t)(fb0 + bl) * 12 + 11) * 128;
            float L = 0.0f;
            #pragma unroll 16
            for (int e = 0; e < 128; ++e)
                L += __half2float(er[e]) * hl_s[lane2 * 129 + e];
            float pre = vs[lane2 * 33 + bl] * L;
            #pragma unroll
            for (int off = 32; off > 0; off >>= 1)
                pre += __shfl_down(pre, off);
            if (lane2 == 0) out[fb0 + bl] = pre;
        }
    }
}

extern "C" void kernel_launch(void* const* d_in, const int* in_sizes, int n_in,
                              void* d_out, int out_size, void* d_ws, size_t ws_size,
                              hipStream_t stream) {
    const float* x  = (const float*)d_in[0];
    const float* W1 = (const float*)d_in[1];
    const float* b1 = (const float*)d_in[2];
    const float* W2 = (const float*)d_in[3];
    const float* b2 = (const float*)d_in[4];
    const float* Hf = (const float*)d_in[5];
    const float* Hm = (const float*)d_in[6];
    const float* HL = (const float*)d_in[7];
    float* out = (float*)d_out;
    (void)in_sizes; (void)n_in; (void)out_size;

    char* ws = (char*)d_ws;
    __half* encH        = (__half*)(ws + O_ENC);
    unsigned short* HmH = (unsigned short*)(ws + O_HMH);
    unsigned short* HmL = (unsigned short*)(ws + O_HML);
    __half* w1f         = (__half*)(ws + O_W1F);
    __half* w2f         = (__half*)(ws + O_W2F);
    float* v0           = (float*)(ws + O_V0);
    float* vT           = (float*)(ws + O_V0);   // fallback alias

    const bool part = (ws_size >= NEED_PARTIAL);

    prep_kernel<<<dim3(5216), dim3(256), 0, stream>>>(W1, W2, Hm, w1f, w2f, HmH, HmL);
    enc_kernel<<<dim3(1536), dim3(256), 0, stream>>>(x, b1, b2, w1f, w2f, encH);

    if (part) {
        float* pA = (float*)(ws + O_PA);
        float* pB = (float*)(ws + O_PB);
        fused_chain<<<dim3(256), dim3(512), 0, stream>>>(
            HmH, HmL, encH, Hf, HL, v0, pA, pB, out);
    } else {
        init_kernel<<<dim3(128), dim3(256), 0, stream>>>(encH, Hf, v0);
        float* vA = (float*)(ws + O_VA);
        float* vB = (float*)(ws + O_VB);
        const float* cur = v0;
        for (int t = 1; t <= 10; ++t) {
            float* nxt = (t & 1) ? vA : vB;
            hipMemsetAsync(nxt, 0, (size_t)64 * B_ALL * sizeof(float), stream);
            chain_step<<<dim3(512), dim3(256), 0, stream>>>(
                HmH + (size_t)(t - 1) * 524288, HmL + (size_t)(t - 1) * 524288,
                encH, cur, 1, nxt, 0, t);
            cur = nxt;
        }
        reduce_t_kernel<<<dim3(128), dim3(256), 0, stream>>>(cur, 1, vT);
        final_kernel<<<dim3(512), dim3(64), 0, stream>>>(encH, HL, vT, out);
    }
}

// Round 4
// 847.777 us; speedup vs baseline: 2.0441x; 1.3083x over previous
//
#include <hip/hip_runtime.h>
#include <hip/hip_fp16.h>

// Hankel MPS, round 9: r6 compute structure + r8 fence-free barrier.
//
// Round-7/8 post-mortem: launch_bounds(512,4) forced VGPR=64; chain needs
// ~190 live regs/wave -> B-frags+accumulators spilled to scratch in the
// e-loop -> +1.4 GB HBM traffic (FETCH 1.1GB/WRITE 616MB), MfmaUtil 10%.
// Round-6 (256thr, VGPR 128) had clean 354MB traffic; its 1691us was the
// fence-poisoned barrier (buffer_inv per spin iteration).
//
// Round-9 = the good halves of each:
//  - compute: 512 blocks x 256 thr (4 waves), 8 e-groups, 8 private partials,
//    launch_bounds(256,2) -> VGPR 128, zero spills (r6-verified).
//  - sync: fence-FREE sense-reversal barrier; cross-block partials move via
//    agent-scope RELAXED atomics (sc1 = L2-bypass, served by Infinity Cache).
//    release = __syncthreads' implicit vmcnt(0) drain; acquire = none needed.
//    No wbl2/inv anywhere -> L2 stays warm for H/encH all 10 steps.
//
// ws (partial path, 82.0 MB): encH 25.17M | HmH 10.49M | HmL 10.49M |
//   w1f 64K | w2f 128K | v0 2M | vPartA 16.78M | vPartB 16.78M

#define B_ALL 8192
#define TT    12

typedef short bfrag __attribute__((ext_vector_type(8)));      // 8 bf16
typedef _Float16 hfrag __attribute__((ext_vector_type(8)));   // 8 fp16
typedef float ffrag __attribute__((ext_vector_type(16)));     // 32x32 C/D

#define O_ENC   0ULL
#define O_HMH   25165824ULL
#define O_HML   35651584ULL
#define O_W1F   46137344ULL
#define O_W2F   46202880ULL
#define O_V0    46333952ULL            // 2 MB (v0; reused as vT in fallback)
#define O_PA    48431104ULL            // 16 MB (8 partials x 2MB)
#define O_PB    65208320ULL            // 16 MB
#define NEED_PARTIAL 81985536ULL
#define O_VA    48431104ULL            // atomic path: 2 MB
#define O_VB    50528256ULL            // atomic path: 2 MB

__device__ __forceinline__ unsigned short bf16_rne(float f) {
    unsigned int u = __builtin_bit_cast(unsigned int, f);
    unsigned int r = (u + 0x7fffu + ((u >> 16) & 1u)) >> 16;
    return (unsigned short)r;
}
__device__ __forceinline__ float bf16_f32(unsigned short h) {
    unsigned int u = ((unsigned int)h) << 16;
    return __builtin_bit_cast(float, u);
}

// sc1 (device-coherent) accessors for cross-block partial buffers.
__device__ __forceinline__ void st_f1_sc1(float* p, float v) {
    __hip_atomic_store(p, v, __ATOMIC_RELAXED, __HIP_MEMORY_SCOPE_AGENT);
}
__device__ __forceinline__ float2 ld_f2_sc1(const float* p) {
    unsigned long long u = __hip_atomic_load((unsigned long long*)(size_t)p,
                                             __ATOMIC_RELAXED,
                                             __HIP_MEMORY_SCOPE_AGENT);
    return __builtin_bit_cast(float2, u);
}

// ---------------- prep (unchanged) ----------------
__global__ __launch_bounds__(256)
void prep_kernel(const float* __restrict__ W1, const float* __restrict__ W2,
                 const float* __restrict__ Hm,
                 __half* __restrict__ w1f, __half* __restrict__ w2f,
                 unsigned short* __restrict__ Hh, unsigned short* __restrict__ Hl)
{
    const long long N_W1 = 32768, N_W2 = 65536, N_H = 10LL * 128 * 4096;
    const long long total = N_W1 + N_W2 + N_H;
    const long long stride = (long long)gridDim.x * blockDim.x;
    for (long long idx = (long long)blockIdx.x * blockDim.x + threadIdx.x;
         idx < total; idx += stride) {
        if (idx < N_W1) {
            const int w = (int)idx;
            const int jn = w >> 11, ks = (w >> 9) & 3, half = (w >> 8) & 1;
            const int jl = (w >> 3) & 31, jj = w & 7;
            const int j = jn * 32 + jl, d = ks * 16 + half * 8 + jj;
            w1f[w] = __float2half(W1[j * 64 + d]);
        } else if (idx < N_W1 + N_W2) {
            const int w = (int)(idx - N_W1);
            const int en = w >> 14, ks2g = (w >> 9) & 31, half = (w >> 8) & 1;
            const int el = (w >> 3) & 31, jj = w & 7;
            const int e = en * 32 + el, j = ks2g * 16 + half * 8 + jj;
            w2f[w] = __float2half(W2[e * 512 + j]);
        } else {
            const long long q = idx - N_W1 - N_W2;
            const int t = (int)(q / 524288);
            const int rem = (int)(q % 524288);
            const int e = rem >> 12;
            const int f = rem & 4095;
            const int mf = f >> 11, s = (f >> 9) & 3, half = (f >> 8) & 1;
            const int l = (f >> 3) & 31, j = f & 7;
            const int p = s * 16 + half * 8 + j;
            const int r = mf * 32 + l;
            const float val = Hm[(((long long)t * 64 + p) * 128 + e) * 64 + r];
            const unsigned short hi = bf16_rne(val);
            const unsigned short lo = bf16_rne(val - bf16_f32(hi));
            Hh[q] = hi;
            Hl[q] = lo;
        }
    }
}

// ---------------- encoder (unchanged) ----------------
__global__ __launch_bounds__(256)
void enc_kernel(const float* __restrict__ x,
                const float* __restrict__ b1, const float* __restrict__ b2,
                const __half* __restrict__ w1f, const __half* __restrict__ w2f,
                __half* __restrict__ encH)
{
    __shared__ __align__(16) unsigned char smem[17408];
    float* x_s  = (float*)smem;
    __half* h_s = (__half*)smem;

    const int tid   = threadIdx.x;
    const int wv    = tid >> 6;
    const int lane  = tid & 63;
    const int l32   = lane & 31;
    const int half  = lane >> 5;
    const int msub  = wv >> 1;
    const int nhalf = wv & 1;
    const int m0    = blockIdx.x * 64;

    #pragma unroll
    for (int i = 0; i < 4; ++i) {
        const int f4 = i * 256 + tid;
        const int r = f4 >> 4, c4 = (f4 & 15) * 4;
        *(float4*)&x_s[r * 68 + c4] =
            *(const float4*)&x[(long long)(m0 + r) * 64 + c4];
    }
    __syncthreads();

    hfrag xa[4];
    #pragma unroll
    for (int ks = 0; ks < 4; ++ks) {
        const float* src = &x_s[(msub * 32 + l32) * 68 + ks * 16 + half * 8];
        const float4 a = *(const float4*)src;
        const float4 b = *(const float4*)(src + 4);
        hfrag v;
        v[0] = (_Float16)a.x; v[1] = (_Float16)a.y;
        v[2] = (_Float16)a.z; v[3] = (_Float16)a.w;
        v[4] = (_Float16)b.x; v[5] = (_Float16)b.y;
        v[6] = (_Float16)b.z; v[7] = (_Float16)b.w;
        xa[ks] = v;
    }
    __syncthreads();

    ffrag c2[2];
    c2[0] = 0.0f; c2[1] = 0.0f;

    for (int chunk = 0; chunk < 4; ++chunk) {
        ffrag c1[2];
        float b1j[2];
        #pragma unroll
        for (int nf = 0; nf < 2; ++nf) {
            const int jn = chunk * 4 + nhalf * 2 + nf;
            b1j[nf] = b1[jn * 32 + l32];
            ffrag acc = 0.0f;
            #pragma unroll
            for (int ks = 0; ks < 4; ++ks) {
                const hfrag bh = *(const hfrag*)(w1f + (jn * 4 + ks) * 512
                                                 + half * 256 + l32 * 8);
                acc = __builtin_amdgcn_mfma_f32_32x32x16_f16(xa[ks], bh, acc, 0, 0, 0);
            }
            c1[nf] = acc;
        }
        __syncthreads();
        #pragma unroll
        for (int nf = 0; nf < 2; ++nf) {
            #pragma unroll
            for (int i2 = 0; i2 < 16; ++i2) {
                const int m_row = (i2 & 3) + 8 * (i2 >> 2) + 4 * half;
                const float v = fmaxf(c1[nf][i2] + b1j[nf], 0.0f);
                h_s[(msub * 32 + m_row) * 136 + nhalf * 64 + nf * 32 + l32] =
                    __float2half(v);
            }
        }
        __syncthreads();
        #pragma unroll
        for (int ks2 = 0; ks2 < 8; ++ks2) {
            const hfrag a = *(const hfrag*)&h_s[(msub * 32 + l32) * 136
                                                + ks2 * 16 + half * 8];
            const int ks2g = chunk * 8 + ks2;
            #pragma unroll
            for (int ef = 0; ef < 2; ++ef) {
                const int en = nhalf * 2 + ef;
                const hfrag b = *(const hfrag*)(w2f + (en * 32 + ks2g) * 512
                                                + half * 256 + l32 * 8);
                c2[ef] = __builtin_amdgcn_mfma_f32_32x32x16_f16(a, b, c2[ef], 0, 0, 0);
            }
        }
    }

    #pragma unroll
    for (int ef = 0; ef < 2; ++ef) {
        const int e = nhalf * 64 + ef * 32 + l32;
        const float b2e = b2[e];
        #pragma unroll
        for (int i2 = 0; i2 < 16; ++i2) {
            const int m_row = (i2 & 3) + 8 * (i2 >> 2) + 4 * half;
            const int m_g = m0 + msub * 32 + m_row;
            encH[(long long)m_g * 128 + e] =
                __float2half(fmaxf(c2[ef][i2] + b2e, 0.0f));
        }
    }
}

// ---------------- init (fallback path) ----------------
__global__ __launch_bounds__(256, 2)
void init_kernel(const __half* __restrict__ encH, const float* __restrict__ Hf,
                 float* __restrict__ vOut)   // [64][8192]
{
    __shared__ float enc_s[64 * 129];   // [b][e]
    const int tid = threadIdx.x;
    const int b0 = blockIdx.x * 64;     // grid 128
    {
        const int b = tid >> 2, ec = (tid & 3) * 32;
        const __half* er = encH + ((size_t)(b0 + b) * 12 + 0) * 128 + ec;
        #pragma unroll
        for (int q = 0; q < 4; ++q) {
            uint4 u = *(const uint4*)(er + q * 8);
            const __half* hp = (const __half*)&u;
            #pragma unroll
            for (int j = 0; j < 8; ++j)
                enc_s[b * 129 + ec + q * 8 + j] = __half2float(hp[j]);
        }
    }
    __syncthreads();
    const int wv = tid >> 6, lane = tid & 63;
    const int b = b0 + lane;
    for (int pc = 0; pc < 16; pc += 4) {
        const int p = wv * 16 + pc;
        float a0 = 0, a1 = 0, a2 = 0, a3 = 0;
        for (int e = 0; e < 128; ++e) {
            const float ev = enc_s[lane * 129 + e];
            const float4 h = *(const float4*)&Hf[e * 64 + p];   // wave-uniform
            a0 += ev * h.x; a1 += ev * h.y; a2 += ev * h.z; a3 += ev * h.w;
        }
        vOut[(size_t)(p + 0) * B_ALL + b] = a0;
        vOut[(size_t)(p + 1) * B_ALL + b] = a1;
        vOut[(size_t)(p + 2) * B_ALL + b] = a2;
        vOut[(size_t)(p + 3) * B_ALL + b] = a3;
    }
}

// ---------------- chain step (fallback path, unchanged) ----------------
__global__ __launch_bounds__(256, 2)
void chain_step(const unsigned short* __restrict__ Hsh,  // this t: [128e][4096]
                const unsigned short* __restrict__ Hsl,
                const __half* __restrict__ encH,
                const float* __restrict__ vIn, int nIn,   // nIn partials [p][b]
                float* __restrict__ vOut, int partStride, // 0 => atomicAdd flat
                int t)
{
    __shared__ float vsum[64 * 132];    // [p][b0..b0+127]
    __shared__ float enc_s[16 * 132];   // [e][b]

    const int tid = threadIdx.x;
    const int b0 = (blockIdx.x & 63) * 128;
    const int eg = blockIdx.x >> 6;
    const int e0 = eg * 16;

    #pragma unroll
    for (int k = 0; k < 8; ++k) {
        const int p  = (tid >> 5) + k * 8;
        const int bl = (tid & 31) * 4;
        float4 s = {0.f, 0.f, 0.f, 0.f};
        for (int g = 0; g < nIn; ++g) {
            const float4 u = *(const float4*)&vIn[(size_t)g * 524288
                                                  + (size_t)p * B_ALL + b0 + bl];
            s.x += u.x; s.y += u.y; s.z += u.z; s.w += u.w;
        }
        *(float4*)&vsum[p * 132 + bl] = s;
    }
    if (tid < 128) {
        const __half* er = encH + ((size_t)(b0 + tid) * 12 + t) * 128 + e0;
        uint4 u0 = *(const uint4*)er;
        uint4 u1 = *(const uint4*)(er + 8);
        const __half* h0 = (const __half*)&u0;
        const __half* h1 = (const __half*)&u1;
        #pragma unroll
        for (int el = 0; el < 8; ++el) enc_s[el * 132 + tid] = __half2float(h0[el]);
        #pragma unroll
        for (int el = 0; el < 8; ++el) enc_s[(el + 8) * 132 + tid] = __half2float(h1[el]);
    }
    __syncthreads();

    const int wv = tid >> 6, lane = tid & 63;
    const int l32 = lane & 31, half = lane >> 5;
    const int mf = wv >> 1, bh = wv & 1;

    bfrag vbh_[2][4], vbl_[2][4];
    #pragma unroll
    for (int nf = 0; nf < 2; ++nf) {
        const int bcol = bh * 64 + nf * 32 + l32;
        #pragma unroll
        for (int s = 0; s < 4; ++s) {
            const int p0 = s * 16 + half * 8;
            bfrag hb, lb;
            #pragma unroll
            for (int j = 0; j < 8; ++j) {
                const float f = vsum[(p0 + j) * 132 + bcol];
                const unsigned short hi = bf16_rne(f);
                const unsigned short lo = bf16_rne(f - bf16_f32(hi));
                hb[j] = (short)hi;
                lb[j] = (short)lo;
            }
            vbh_[nf][s] = hb;
            vbl_[nf][s] = lb;
        }
    }

    ffrag z = 0.0f;
    ffrag vn0 = 0.0f, vn1 = 0.0f;

    #pragma unroll 2
    for (int e = 0; e < 16; ++e) {
        const float ev0 = enc_s[e * 132 + bh * 64 + l32];
        const float ev1 = enc_s[e * 132 + bh * 64 + 32 + l32];
        const unsigned short* hbase = Hsh + (size_t)(e0 + e) * 4096;
        const unsigned short* lbase = Hsl + (size_t)(e0 + e) * 4096;
        ffrag wa = z, wb = z;
        #pragma unroll
        for (int s = 0; s < 4; ++s) {
            const int fo = (((mf * 4 + s) * 2 + half) * 32 + l32) * 8;
            const bfrag ah = *(const bfrag*)(hbase + fo);
            const bfrag al = *(const bfrag*)(lbase + fo);
            wa = __builtin_amdgcn_mfma_f32_32x32x16_bf16(ah, vbh_[0][s], wa, 0, 0, 0);
            wa = __builtin_amdgcn_mfma_f32_32x32x16_bf16(ah, vbl_[0][s], wa, 0, 0, 0);
            wa = __builtin_amdgcn_mfma_f32_32x32x16_bf16(al, vbh_[0][s], wa, 0, 0, 0);
            wb = __builtin_amdgcn_mfma_f32_32x32x16_bf16(ah, vbh_[1][s], wb, 0, 0, 0);
            wb = __builtin_amdgcn_mfma_f32_32x32x16_bf16(ah, vbl_[1][s], wb, 0, 0, 0);
            wb = __builtin_amdgcn_mfma_f32_32x32x16_bf16(al, vbh_[1][s], wb, 0, 0, 0);
        }
        vn0 += wa * ev0;
        vn1 += wb * ev1;
    }

    #pragma unroll
    for (int nf = 0; nf < 2; ++nf) {
        const ffrag vv = nf ? vn1 : vn0;
        const int b = b0 + bh * 64 + nf * 32 + l32;
        #pragma unroll
        for (int i = 0; i < 16; ++i) {
            const int r = mf * 32 + (i & 3) + 8 * (i >> 2) + 4 * half;
            if (partStride)
                vOut[(size_t)eg * partStride + (size_t)r * B_ALL + b] = vv[i];
            else
                atomicAdd(&vOut[(size_t)r * B_ALL + b], vv[i]);
        }
    }
}

// ---------------- reduce + transpose (fallback path) ----------------
__global__ __launch_bounds__(256)
void reduce_t_kernel(const float* __restrict__ vIn, int nIn,
                     float* __restrict__ vT)   // [8192][64]
{
    __shared__ float vt[64][68];
    const int tid = threadIdx.x;
    const int b0 = blockIdx.x * 64;   // grid 128
    #pragma unroll
    for (int k = 0; k < 8; ++k) {
        const int p  = (tid >> 5) + k * 8;
        const int bl = (tid & 31) * 2;
        float2 s = {0.f, 0.f};
        for (int g = 0; g < nIn; ++g) {
            const float2 u = *(const float2*)&vIn[(size_t)g * 524288
                                                  + (size_t)p * B_ALL + b0 + bl];
            s.x += u.x; s.y += u.y;
        }
        vt[bl][p] = s.x;
        vt[bl + 1][p] = s.y;
    }
    __syncthreads();
    const int b = tid >> 2, c = (tid & 3) * 16;
    float4* dst = (float4*)&vT[(size_t)(b0 + b) * 64 + c];
    #pragma unroll
    for (int q = 0; q < 4; ++q)
        dst[q] = *(float4*)&vt[b][c + q * 4];
}

// ---------------- final (fallback path) ----------------
__global__ __launch_bounds__(64)
void final_kernel(const __half* __restrict__ encH, const float* __restrict__ HL,
                  const float* __restrict__ vT, float* __restrict__ out)
{
    __shared__ float hl_s[64 * 129];
    const int tid = threadIdx.x;
    const int b0 = blockIdx.x * 16;
    for (int i = 0; i < 128; ++i) {
        const int idx = i * 64 + tid;
        hl_s[(idx >> 7) * 129 + (idx & 127)] = HL[idx];
    }
    __syncthreads();
    const int p = tid;
    for (int bs = 0; bs < 16; ++bs) {
        const int b = b0 + bs;
        const __half* er = encH + (size_t)(b * 12 + 11) * 128;
        float L = 0.0f;
        #pragma unroll 16
        for (int e = 0; e < 128; ++e)
            L += __half2float(er[e]) * hl_s[p * 129 + e];
        float pre = vT[(size_t)b * 64 + p] * L;
        #pragma unroll
        for (int off = 32; off > 0; off >>= 1)
            pre += __shfl_down(pre, off);
        if (tid == 0) out[b] = pre;
    }
}

// ---------------- persistent fused chain ----------------
// Fence-free sense-reversal grid barrier (r8 mechanism, r6 geometry):
//  - cross-block data moves via sc1 (agent-scope relaxed atomics)
//  - release: __syncthreads drains vmcnt(0) (sc1 stores at coherence point)
//  - acquire: nothing (sc1 loads bypass the non-coherent XCD L2)
//  - g_bar reset ordered before g_gen bump via s_waitcnt vmcnt(0)
#define NB_FUSED 512

__device__ unsigned int g_bar = 0u;
__device__ unsigned int g_gen = 0u;

__device__ __forceinline__ void grid_sync_fused() {
    __syncthreads();   // drains vmcnt(0): all waves' sc1 stores completed
    if (threadIdx.x == 0) {
        const unsigned g =
            __hip_atomic_load(&g_gen, __ATOMIC_RELAXED, __HIP_MEMORY_SCOPE_AGENT);
        const unsigned a =
            __hip_atomic_fetch_add(&g_bar, 1u, __ATOMIC_RELAXED,
                                   __HIP_MEMORY_SCOPE_AGENT);
        if (a == NB_FUSED - 1u) {
            __hip_atomic_store(&g_bar, 0u, __ATOMIC_RELAXED,
                               __HIP_MEMORY_SCOPE_AGENT);
            asm volatile("s_waitcnt vmcnt(0)" ::: "memory");  // reset lands first
            __hip_atomic_store(&g_gen, g + 1u, __ATOMIC_RELAXED,
                               __HIP_MEMORY_SCOPE_AGENT);
        } else {
            while (__hip_atomic_load(&g_gen, __ATOMIC_RELAXED,
                                     __HIP_MEMORY_SCOPE_AGENT) == g)
                __builtin_amdgcn_s_sleep(4);
        }
    }
    __syncthreads();
}

// r6 geometry: 512 blocks x 256 thr (4 waves: mf=wv>>1, bh=wv&1).
// Block = (btile: 128 b) x (eg: 16 e). 8 private partials [p][b], 2MB each.
__global__ __launch_bounds__(256, 2)
void fused_chain(const unsigned short* __restrict__ HmH,
                 const unsigned short* __restrict__ HmL,
                 const __half* __restrict__ encH,
                 const float* __restrict__ Hf,
                 const float* __restrict__ HL,
                 float* v0, float* pA, float* pB,
                 float* __restrict__ out)
{
    // LDS overlays: chain: vsum[64][132] (33792 B) + enc[16][132] (8448 B)
    //               init:  enc[64][129] (33024 B)
    //               final: hl[64][129] (33024 B) + vs[64][17] (4352 B)
    __shared__ __align__(16) unsigned char smem[42240];
    const int tid = threadIdx.x;
    const int bid = blockIdx.x;

    // ---- phase 0: init v0 (blocks 0..127, 64 b each) ----
    if (bid < 128) {
        float* encs = (float*)smem;        // [64][129]
        const int b0i = bid * 64;
        {
            const int b = tid >> 2, ec = (tid & 3) * 32;
            const __half* er = encH + ((size_t)(b0i + b) * 12 + 0) * 128 + ec;
            #pragma unroll
            for (int q = 0; q < 4; ++q) {
                uint4 u = *(const uint4*)(er + q * 8);
                const __half* hp = (const __half*)&u;
                #pragma unroll
                for (int j = 0; j < 8; ++j)
                    encs[b * 129 + ec + q * 8 + j] = __half2float(hp[j]);
            }
        }
        __syncthreads();
        const int wvi = tid >> 6, lanei = tid & 63;
        const int b = b0i + lanei;
        for (int pc = 0; pc < 16; pc += 4) {
            const int p = wvi * 16 + pc;
            float a0 = 0, a1 = 0, a2 = 0, a3 = 0;
            for (int e = 0; e < 128; ++e) {
                const float ev = encs[lanei * 129 + e];
                const float4 h = *(const float4*)&Hf[e * 64 + p];  // wave-uniform
                a0 += ev * h.x; a1 += ev * h.y; a2 += ev * h.z; a3 += ev * h.w;
            }
            st_f1_sc1(&v0[(size_t)(p + 0) * B_ALL + b], a0);
            st_f1_sc1(&v0[(size_t)(p + 1) * B_ALL + b], a1);
            st_f1_sc1(&v0[(size_t)(p + 2) * B_ALL + b], a2);
            st_f1_sc1(&v0[(size_t)(p + 3) * B_ALL + b], a3);
        }
    }
    grid_sync_fused();

    // ---- phases 1..10: chain ----
    const int b0 = (bid & 63) * 128;
    const int eg = bid >> 6;
    const int e0 = eg * 16;
    const int wv = tid >> 6, lane = tid & 63;
    const int l32 = lane & 31, half = lane >> 5;
    const int mf = wv >> 1, bh = wv & 1;

    float* vsum  = (float*)smem;               // [64][132]
    float* encs2 = (float*)(smem + 33792);     // [16][132]

    const float* vIn = v0;
    float* vOut = pA;
    const unsigned short* Hsh = HmH;
    const unsigned short* Hsl = HmL;

    #pragma unroll 1
    for (int t = 1; t <= 10; ++t) {
        // stage vsum = sum of partials (sc1 loads; 8-way unrolled for ILP)
        if (t == 1) {
            #pragma unroll
            for (int k = 0; k < 8; ++k) {
                const int p  = (tid >> 5) + k * 8;
                const int bl = (tid & 31) * 4;
                const float* base = &vIn[(size_t)p * B_ALL + b0 + bl];
                const float2 u0 = ld_f2_sc1(base);
                const float2 u1 = ld_f2_sc1(base + 2);
                *(float2*)&vsum[p * 132 + bl]     = u0;
                *(float2*)&vsum[p * 132 + bl + 2] = u1;
            }
        } else {
            #pragma unroll
            for (int k = 0; k < 8; ++k) {
                const int p  = (tid >> 5) + k * 8;
                const int bl = (tid & 31) * 4;
                float2 s01 = {0.f, 0.f}, s23 = {0.f, 0.f};
                #pragma unroll
                for (int g = 0; g < 8; ++g) {
                    const float* base = &vIn[(size_t)g * 524288
                                             + (size_t)p * B_ALL + b0 + bl];
                    const float2 u0 = ld_f2_sc1(base);
                    const float2 u1 = ld_f2_sc1(base + 2);
                    s01.x += u0.x; s01.y += u0.y;
                    s23.x += u1.x; s23.y += u1.y;
                }
                *(float2*)&vsum[p * 132 + bl]     = s01;
                *(float2*)&vsum[p * 132 + bl + 2] = s23;
            }
        }
        // stage enc slice [16 e][128 b]
        if (tid < 128) {
            const __half* er = encH + ((size_t)(b0 + tid) * 12 + t) * 128 + e0;
            uint4 u0 = *(const uint4*)er;
            uint4 u1 = *(const uint4*)(er + 8);
            const __half* h0 = (const __half*)&u0;
            const __half* h1 = (const __half*)&u1;
            #pragma unroll
            for (int el = 0; el < 8; ++el)
                encs2[el * 132 + tid] = __half2float(h0[el]);
            #pragma unroll
            for (int el = 0; el < 8; ++el)
                encs2[(el + 8) * 132 + tid] = __half2float(h1[el]);
        }
        __syncthreads();

        // B-frags: v hi/lo split from LDS (held in registers)
        bfrag vbh_[2][4], vbl_[2][4];
        #pragma unroll
        for (int nf = 0; nf < 2; ++nf) {
            const int bcol = bh * 64 + nf * 32 + l32;
            #pragma unroll
            for (int s = 0; s < 4; ++s) {
                const int p0 = s * 16 + half * 8;
                bfrag hb, lb;
                #pragma unroll
                for (int j = 0; j < 8; ++j) {
                    const float f = vsum[(p0 + j) * 132 + bcol];
                    const unsigned short hi = bf16_rne(f);
                    const unsigned short lo = bf16_rne(f - bf16_f32(hi));
                    hb[j] = (short)hi;
                    lb[j] = (short)lo;
                }
                vbh_[nf][s] = hb;
                vbl_[nf][s] = lb;
            }
        }

        ffrag z = 0.0f;
        ffrag vn0 = 0.0f, vn1 = 0.0f;

        #pragma unroll 2
        for (int e = 0; e < 16; ++e) {
            const float ev0 = encs2[e * 132 + bh * 64 + l32];
            const float ev1 = encs2[e * 132 + bh * 64 + 32 + l32];
            const unsigned short* hbase = Hsh + (size_t)(e0 + e) * 4096;
            const unsigned short* lbase = Hsl + (size_t)(e0 + e) * 4096;
            ffrag wa = z, wb = z;
            #pragma unroll
            for (int s = 0; s < 4; ++s) {
                const int fo = (((mf * 4 + s) * 2 + half) * 32 + l32) * 8;
                const bfrag ah = *(const bfrag*)(hbase + fo);
                const bfrag al = *(const bfrag*)(lbase + fo);
                wa = __builtin_amdgcn_mfma_f32_32x32x16_bf16(ah, vbh_[0][s], wa, 0, 0, 0);
                wa = __builtin_amdgcn_mfma_f32_32x32x16_bf16(ah, vbl_[0][s], wa, 0, 0, 0);
                wa = __builtin_amdgcn_mfma_f32_32x32x16_bf16(al, vbh_[0][s], wa, 0, 0, 0);
                wb = __builtin_amdgcn_mfma_f32_32x32x16_bf16(ah, vbh_[1][s], wb, 0, 0, 0);
                wb = __builtin_amdgcn_mfma_f32_32x32x16_bf16(ah, vbl_[1][s], wb, 0, 0, 0);
                wb = __builtin_amdgcn_mfma_f32_32x32x16_bf16(al, vbh_[1][s], wb, 0, 0, 0);
            }
            vn0 += wa * ev0;
            vn1 += wb * ev1;
        }

        // epilogue: private partial slice (sc1 stores, coalesced per half-wave)
        #pragma unroll
        for (int nf = 0; nf < 2; ++nf) {
            const ffrag vv = nf ? vn1 : vn0;
            const int b = b0 + bh * 64 + nf * 32 + l32;
            #pragma unroll
            for (int i = 0; i < 16; ++i) {
                const int r = mf * 32 + (i & 3) + 8 * (i >> 2) + 4 * half;
                st_f1_sc1(&vOut[(size_t)eg * 524288 + (size_t)r * B_ALL + b],
                          vv[i]);
            }
        }

        grid_sync_fused();

        vIn = vOut;
        vOut = (t & 1) ? pB : pA;
        Hsh += 524288;
        Hsl += 524288;
    }

    // ---- final: all 512 blocks, 16 b each; sum 8 partials in LDS ----
    {
        float* hl_s = (float*)smem;              // [64][129]
        float* vs   = (float*)(smem + 33024);    // [64][17]
        const float* vFin = pB;                  // t=10 (even) wrote pB
        const int fb0 = bid * 16;
        #pragma unroll
        for (int i = 0; i < 32; ++i) {
            const int idx = i * 256 + tid;       // 8192 floats of HL
            hl_s[(idx >> 7) * 129 + (idx & 127)] = HL[idx];
        }
        {
            const int p  = tid >> 2;
            const int bs = (tid & 3) * 4;
            float4 s = {0.f, 0.f, 0.f, 0.f};
            #pragma unroll
            for (int g = 0; g < 8; ++g) {
                const float* base = &vFin[(size_t)g * 524288
                                          + (size_t)p * B_ALL + fb0 + bs];
                const float2 u0 = ld_f2_sc1(base);
                const float2 u1 = ld_f2_sc1(base + 2);
                s.x += u0.x; s.y += u0.y; s.z += u1.x; s.w += u1.y;
            }
            vs[p * 17 + bs + 0] = s.x;
            vs[p * 17 + bs + 1] = s.y;
            vs[p * 17 + bs + 2] = s.z;
            vs[p * 17 + bs + 3] = s.w;
        }
        __syncthreads();
        const int wv2 = tid >> 6, lane2 = tid & 63;
        #pragma unroll
        for (int q = 0; q < 4; ++q) {
            const int bl = wv2 * 4 + q;
            const __half* er = encH + ((size_t)(fb0 + bl) * 12 + 11) * 128;
            float L = 0.0f;
            #pragma unroll 16
            for (int e = 0; e < 128; ++e)
                L += __half2float(er[e]) * hl_s[lane2 * 129 + e];
            float pre = vs[lane2 * 17 + bl] * L;
            #pragma unroll
            for (int off = 32; off > 0; off >>= 1)
                pre += __shfl_down(pre, off);
            if (lane2 == 0) out[fb0 + bl] = pre;
        }
    }
}

extern "C" void kernel_launch(void* const* d_in, const int* in_sizes, int n_in,
                              void* d_out, int out_size, void* d_ws, size_t ws_size,
                              hipStream_t stream) {
    const float* x  = (const float*)d_in[0];
    const float* W1 = (const float*)d_in[1];
    const float* b1 = (const float*)d_in[2];
    const float* W2 = (const float*)d_in[3];
    const float* b2 = (const float*)d_in[4];
    const float* Hf = (const float*)d_in[5];
    const float* Hm = (const float*)d_in[6];
    const float* HL = (const float*)d_in[7];
    float* out = (float*)d_out;
    (void)in_sizes; (void)n_in; (void)out_size;

    char* ws = (char*)d_ws;
    __half* encH        = (__half*)(ws + O_ENC);
    unsigned short* HmH = (unsigned short*)(ws + O_HMH);
    unsigned short* HmL = (unsigned short*)(ws + O_HML);
    __half* w1f         = (__half*)(ws + O_W1F);
    __half* w2f         = (__half*)(ws + O_W2F);
    float* v0           = (float*)(ws + O_V0);
    float* vT           = (float*)(ws + O_V0);   // fallback alias

    const bool part = (ws_size >= NEED_PARTIAL);

    prep_kernel<<<dim3(5216), dim3(256), 0, stream>>>(W1, W2, Hm, w1f, w2f, HmH, HmL);
    enc_kernel<<<dim3(1536), dim3(256), 0, stream>>>(x, b1, b2, w1f, w2f, encH);

    if (part) {
        float* pA = (float*)(ws + O_PA);
        float* pB = (float*)(ws + O_PB);
        fused_chain<<<dim3(512), dim3(256), 0, stream>>>(
            HmH, HmL, encH, Hf, HL, v0, pA, pB, out);
    } else {
        init_kernel<<<dim3(128), dim3(256), 0, stream>>>(encH, Hf, v0);
        float* vA = (float*)(ws + O_VA);
        float* vB = (float*)(ws + O_VB);
        const float* cur = v0;
        for (int t = 1; t <= 10; ++t) {
            float* nxt = (t & 1) ? vA : vB;
            hipMemsetAsync(nxt, 0, (size_t)64 * B_ALL * sizeof(float), stream);
            chain_step<<<dim3(512), dim3(256), 0, stream>>>(
                HmH + (size_t)(t - 1) * 524288, HmL + (size_t)(t - 1) * 524288,
                encH, cur, 1, nxt, 0, t);
            cur = nxt;
        }
        reduce_t_kernel<<<dim3(128), dim3(256), 0, stream>>>(cur, 1, vT);
        final_kernel<<<dim3(512), dim3(64), 0, stream>>>(encH, HL, vT, out);
    }
}

// Round 5
// 577.168 us; speedup vs baseline: 3.0025x; 1.4689x over previous
//
#include <hip/hip_runtime.h>
#include <hip/hip_fp16.h>

// Hankel MPS, round 10: barrier v3 (hierarchical monotonic + throttled poll).
//
// Round-9 post-mortem: traffic clean (353MB), VGPR 128, no spills — but
// fused_chain 763us with MfmaUtil 14%: ~60us/step of MALL contention from
// the barrier: 512 same-line RMW arrivals (~25-50us queued) + 512 pollers
// at s_sleep(4)=107ns -> 4.8G reads/s on one line, queuing against the
// arrivals and the sc1 staging loads.
//
// Round-10 (single variable): barrier v3 —
//  - arrival: 64 group counters (128B apart) + root; 8 blocks/group.
//    Same-line RMW queue depth 512 -> 8; total RMWs 512 -> 128.
//  - monotonic counters ((a&7)==7 / (r&63)==63): no resets, no reset race.
//  - polling: s_sleep(32) ~0.85us -> ~8x less poll pressure.
// Data handoff unchanged: sc1 (agent-relaxed) partials, release via
// __syncthreads' vmcnt(0) drain, no wbl2/inv anywhere.
//
// ws (partial path, 82.0 MB): encH 25.17M | HmH 10.49M | HmL 10.49M |
//   w1f 64K | w2f 128K | v0 2M | vPartA 16.78M | vPartB 16.78M

#define B_ALL 8192
#define TT    12

typedef short bfrag __attribute__((ext_vector_type(8)));      // 8 bf16
typedef _Float16 hfrag __attribute__((ext_vector_type(8)));   // 8 fp16
typedef float ffrag __attribute__((ext_vector_type(16)));     // 32x32 C/D

#define O_ENC   0ULL
#define O_HMH   25165824ULL
#define O_HML   35651584ULL
#define O_W1F   46137344ULL
#define O_W2F   46202880ULL
#define O_V0    46333952ULL            // 2 MB (v0; reused as vT in fallback)
#define O_PA    48431104ULL            // 16 MB (8 partials x 2MB)
#define O_PB    65208320ULL            // 16 MB
#define NEED_PARTIAL 81985536ULL
#define O_VA    48431104ULL            // atomic path: 2 MB
#define O_VB    50528256ULL            // atomic path: 2 MB

__device__ __forceinline__ unsigned short bf16_rne(float f) {
    unsigned int u = __builtin_bit_cast(unsigned int, f);
    unsigned int r = (u + 0x7fffu + ((u >> 16) & 1u)) >> 16;
    return (unsigned short)r;
}
__device__ __forceinline__ float bf16_f32(unsigned short h) {
    unsigned int u = ((unsigned int)h) << 16;
    return __builtin_bit_cast(float, u);
}

// sc1 (device-coherent) accessors for cross-block partial buffers.
__device__ __forceinline__ void st_f1_sc1(float* p, float v) {
    __hip_atomic_store(p, v, __ATOMIC_RELAXED, __HIP_MEMORY_SCOPE_AGENT);
}
__device__ __forceinline__ float2 ld_f2_sc1(const float* p) {
    unsigned long long u = __hip_atomic_load((unsigned long long*)(size_t)p,
                                             __ATOMIC_RELAXED,
                                             __HIP_MEMORY_SCOPE_AGENT);
    return __builtin_bit_cast(float2, u);
}

// ---------------- prep (unchanged) ----------------
__global__ __launch_bounds__(256)
void prep_kernel(const float* __restrict__ W1, const float* __restrict__ W2,
                 const float* __restrict__ Hm,
                 __half* __restrict__ w1f, __half* __restrict__ w2f,
                 unsigned short* __restrict__ Hh, unsigned short* __restrict__ Hl)
{
    const long long N_W1 = 32768, N_W2 = 65536, N_H = 10LL * 128 * 4096;
    const long long total = N_W1 + N_W2 + N_H;
    const long long stride = (long long)gridDim.x * blockDim.x;
    for (long long idx = (long long)blockIdx.x * blockDim.x + threadIdx.x;
         idx < total; idx += stride) {
        if (idx < N_W1) {
            const int w = (int)idx;
            const int jn = w >> 11, ks = (w >> 9) & 3, half = (w >> 8) & 1;
            const int jl = (w >> 3) & 31, jj = w & 7;
            const int j = jn * 32 + jl, d = ks * 16 + half * 8 + jj;
            w1f[w] = __float2half(W1[j * 64 + d]);
        } else if (idx < N_W1 + N_W2) {
            const int w = (int)(idx - N_W1);
            const int en = w >> 14, ks2g = (w >> 9) & 31, half = (w >> 8) & 1;
            const int el = (w >> 3) & 31, jj = w & 7;
            const int e = en * 32 + el, j = ks2g * 16 + half * 8 + jj;
            w2f[w] = __float2half(W2[e * 512 + j]);
        } else {
            const long long q = idx - N_W1 - N_W2;
            const int t = (int)(q / 524288);
            const int rem = (int)(q % 524288);
            const int e = rem >> 12;
            const int f = rem & 4095;
            const int mf = f >> 11, s = (f >> 9) & 3, half = (f >> 8) & 1;
            const int l = (f >> 3) & 31, j = f & 7;
            const int p = s * 16 + half * 8 + j;
            const int r = mf * 32 + l;
            const float val = Hm[(((long long)t * 64 + p) * 128 + e) * 64 + r];
            const unsigned short hi = bf16_rne(val);
            const unsigned short lo = bf16_rne(val - bf16_f32(hi));
            Hh[q] = hi;
            Hl[q] = lo;
        }
    }
}

// ---------------- encoder (unchanged) ----------------
__global__ __launch_bounds__(256)
void enc_kernel(const float* __restrict__ x,
                const float* __restrict__ b1, const float* __restrict__ b2,
                const __half* __restrict__ w1f, const __half* __restrict__ w2f,
                __half* __restrict__ encH)
{
    __shared__ __align__(16) unsigned char smem[17408];
    float* x_s  = (float*)smem;
    __half* h_s = (__half*)smem;

    const int tid   = threadIdx.x;
    const int wv    = tid >> 6;
    const int lane  = tid & 63;
    const int l32   = lane & 31;
    const int half  = lane >> 5;
    const int msub  = wv >> 1;
    const int nhalf = wv & 1;
    const int m0    = blockIdx.x * 64;

    #pragma unroll
    for (int i = 0; i < 4; ++i) {
        const int f4 = i * 256 + tid;
        const int r = f4 >> 4, c4 = (f4 & 15) * 4;
        *(float4*)&x_s[r * 68 + c4] =
            *(const float4*)&x[(long long)(m0 + r) * 64 + c4];
    }
    __syncthreads();

    hfrag xa[4];
    #pragma unroll
    for (int ks = 0; ks < 4; ++ks) {
        const float* src = &x_s[(msub * 32 + l32) * 68 + ks * 16 + half * 8];
        const float4 a = *(const float4*)src;
        const float4 b = *(const float4*)(src + 4);
        hfrag v;
        v[0] = (_Float16)a.x; v[1] = (_Float16)a.y;
        v[2] = (_Float16)a.z; v[3] = (_Float16)a.w;
        v[4] = (_Float16)b.x; v[5] = (_Float16)b.y;
        v[6] = (_Float16)b.z; v[7] = (_Float16)b.w;
        xa[ks] = v;
    }
    __syncthreads();

    ffrag c2[2];
    c2[0] = 0.0f; c2[1] = 0.0f;

    for (int chunk = 0; chunk < 4; ++chunk) {
        ffrag c1[2];
        float b1j[2];
        #pragma unroll
        for (int nf = 0; nf < 2; ++nf) {
            const int jn = chunk * 4 + nhalf * 2 + nf;
            b1j[nf] = b1[jn * 32 + l32];
            ffrag acc = 0.0f;
            #pragma unroll
            for (int ks = 0; ks < 4; ++ks) {
                const hfrag bh = *(const hfrag*)(w1f + (jn * 4 + ks) * 512
                                                 + half * 256 + l32 * 8);
                acc = __builtin_amdgcn_mfma_f32_32x32x16_f16(xa[ks], bh, acc, 0, 0, 0);
            }
            c1[nf] = acc;
        }
        __syncthreads();
        #pragma unroll
        for (int nf = 0; nf < 2; ++nf) {
            #pragma unroll
            for (int i2 = 0; i2 < 16; ++i2) {
                const int m_row = (i2 & 3) + 8 * (i2 >> 2) + 4 * half;
                const float v = fmaxf(c1[nf][i2] + b1j[nf], 0.0f);
                h_s[(msub * 32 + m_row) * 136 + nhalf * 64 + nf * 32 + l32] =
                    __float2half(v);
            }
        }
        __syncthreads();
        #pragma unroll
        for (int ks2 = 0; ks2 < 8; ++ks2) {
            const hfrag a = *(const hfrag*)&h_s[(msub * 32 + l32) * 136
                                                + ks2 * 16 + half * 8];
            const int ks2g = chunk * 8 + ks2;
            #pragma unroll
            for (int ef = 0; ef < 2; ++ef) {
                const int en = nhalf * 2 + ef;
                const hfrag b = *(const hfrag*)(w2f + (en * 32 + ks2g) * 512
                                                + half * 256 + l32 * 8);
                c2[ef] = __builtin_amdgcn_mfma_f32_32x32x16_f16(a, b, c2[ef], 0, 0, 0);
            }
        }
    }

    #pragma unroll
    for (int ef = 0; ef < 2; ++ef) {
        const int e = nhalf * 64 + ef * 32 + l32;
        const float b2e = b2[e];
        #pragma unroll
        for (int i2 = 0; i2 < 16; ++i2) {
            const int m_row = (i2 & 3) + 8 * (i2 >> 2) + 4 * half;
            const int m_g = m0 + msub * 32 + m_row;
            encH[(long long)m_g * 128 + e] =
                __float2half(fmaxf(c2[ef][i2] + b2e, 0.0f));
        }
    }
}

// ---------------- init (fallback path) ----------------
__global__ __launch_bounds__(256, 2)
void init_kernel(const __half* __restrict__ encH, const float* __restrict__ Hf,
                 float* __restrict__ vOut)   // [64][8192]
{
    __shared__ float enc_s[64 * 129];   // [b][e]
    const int tid = threadIdx.x;
    const int b0 = blockIdx.x * 64;     // grid 128
    {
        const int b = tid >> 2, ec = (tid & 3) * 32;
        const __half* er = encH + ((size_t)(b0 + b) * 12 + 0) * 128 + ec;
        #pragma unroll
        for (int q = 0; q < 4; ++q) {
            uint4 u = *(const uint4*)(er + q * 8);
            const __half* hp = (const __half*)&u;
            #pragma unroll
            for (int j = 0; j < 8; ++j)
                enc_s[b * 129 + ec + q * 8 + j] = __half2float(hp[j]);
        }
    }
    __syncthreads();
    const int wv = tid >> 6, lane = tid & 63;
    const int b = b0 + lane;
    for (int pc = 0; pc < 16; pc += 4) {
        const int p = wv * 16 + pc;
        float a0 = 0, a1 = 0, a2 = 0, a3 = 0;
        for (int e = 0; e < 128; ++e) {
            const float ev = enc_s[lane * 129 + e];
            const float4 h = *(const float4*)&Hf[e * 64 + p];   // wave-uniform
            a0 += ev * h.x; a1 += ev * h.y; a2 += ev * h.z; a3 += ev * h.w;
        }
        vOut[(size_t)(p + 0) * B_ALL + b] = a0;
        vOut[(size_t)(p + 1) * B_ALL + b] = a1;
        vOut[(size_t)(p + 2) * B_ALL + b] = a2;
        vOut[(size_t)(p + 3) * B_ALL + b] = a3;
    }
}

// ---------------- chain step (fallback path, unchanged) ----------------
__global__ __launch_bounds__(256, 2)
void chain_step(const unsigned short* __restrict__ Hsh,  // this t: [128e][4096]
                const unsigned short* __restrict__ Hsl,
                const __half* __restrict__ encH,
                const float* __restrict__ vIn, int nIn,   // nIn partials [p][b]
                float* __restrict__ vOut, int partStride, // 0 => atomicAdd flat
                int t)
{
    __shared__ float vsum[64 * 132];    // [p][b0..b0+127]
    __shared__ float enc_s[16 * 132];   // [e][b]

    const int tid = threadIdx.x;
    const int b0 = (blockIdx.x & 63) * 128;
    const int eg = blockIdx.x >> 6;
    const int e0 = eg * 16;

    #pragma unroll
    for (int k = 0; k < 8; ++k) {
        const int p  = (tid >> 5) + k * 8;
        const int bl = (tid & 31) * 4;
        float4 s = {0.f, 0.f, 0.f, 0.f};
        for (int g = 0; g < nIn; ++g) {
            const float4 u = *(const float4*)&vIn[(size_t)g * 524288
                                                  + (size_t)p * B_ALL + b0 + bl];
            s.x += u.x; s.y += u.y; s.z += u.z; s.w += u.w;
        }
        *(float4*)&vsum[p * 132 + bl] = s;
    }
    if (tid < 128) {
        const __half* er = encH + ((size_t)(b0 + tid) * 12 + t) * 128 + e0;
        uint4 u0 = *(const uint4*)er;
        uint4 u1 = *(const uint4*)(er + 8);
        const __half* h0 = (const __half*)&u0;
        const __half* h1 = (const __half*)&u1;
        #pragma unroll
        for (int el = 0; el < 8; ++el) enc_s[el * 132 + tid] = __half2float(h0[el]);
        #pragma unroll
        for (int el = 0; el < 8; ++el) enc_s[(el + 8) * 132 + tid] = __half2float(h1[el]);
    }
    __syncthreads();

    const int wv = tid >> 6, lane = tid & 63;
    const int l32 = lane & 31, half = lane >> 5;
    const int mf = wv >> 1, bh = wv & 1;

    bfrag vbh_[2][4], vbl_[2][4];
    #pragma unroll
    for (int nf = 0; nf < 2; ++nf) {
        const int bcol = bh * 64 + nf * 32 + l32;
        #pragma unroll
        for (int s = 0; s < 4; ++s) {
            const int p0 = s * 16 + half * 8;
            bfrag hb, lb;
            #pragma unroll
            for (int j = 0; j < 8; ++j) {
                const float f = vsum[(p0 + j) * 132 + bcol];
                const unsigned short hi = bf16_rne(f);
                const unsigned short lo = bf16_rne(f - bf16_f32(hi));
                hb[j] = (short)hi;
                lb[j] = (short)lo;
            }
            vbh_[nf][s] = hb;
            vbl_[nf][s] = lb;
        }
    }

    ffrag z = 0.0f;
    ffrag vn0 = 0.0f, vn1 = 0.0f;

    #pragma unroll 2
    for (int e = 0; e < 16; ++e) {
        const float ev0 = enc_s[e * 132 + bh * 64 + l32];
        const float ev1 = enc_s[e * 132 + bh * 64 + 32 + l32];
        const unsigned short* hbase = Hsh + (size_t)(e0 + e) * 4096;
        const unsigned short* lbase = Hsl + (size_t)(e0 + e) * 4096;
        ffrag wa = z, wb = z;
        #pragma unroll
        for (int s = 0; s < 4; ++s) {
            const int fo = (((mf * 4 + s) * 2 + half) * 32 + l32) * 8;
            const bfrag ah = *(const bfrag*)(hbase + fo);
            const bfrag al = *(const bfrag*)(lbase + fo);
            wa = __builtin_amdgcn_mfma_f32_32x32x16_bf16(ah, vbh_[0][s], wa, 0, 0, 0);
            wa = __builtin_amdgcn_mfma_f32_32x32x16_bf16(ah, vbl_[0][s], wa, 0, 0, 0);
            wa = __builtin_amdgcn_mfma_f32_32x32x16_bf16(al, vbh_[0][s], wa, 0, 0, 0);
            wb = __builtin_amdgcn_mfma_f32_32x32x16_bf16(ah, vbh_[1][s], wb, 0, 0, 0);
            wb = __builtin_amdgcn_mfma_f32_32x32x16_bf16(ah, vbl_[1][s], wb, 0, 0, 0);
            wb = __builtin_amdgcn_mfma_f32_32x32x16_bf16(al, vbh_[1][s], wb, 0, 0, 0);
        }
        vn0 += wa * ev0;
        vn1 += wb * ev1;
    }

    #pragma unroll
    for (int nf = 0; nf < 2; ++nf) {
        const ffrag vv = nf ? vn1 : vn0;
        const int b = b0 + bh * 64 + nf * 32 + l32;
        #pragma unroll
        for (int i = 0; i < 16; ++i) {
            const int r = mf * 32 + (i & 3) + 8 * (i >> 2) + 4 * half;
            if (partStride)
                vOut[(size_t)eg * partStride + (size_t)r * B_ALL + b] = vv[i];
            else
                atomicAdd(&vOut[(size_t)r * B_ALL + b], vv[i]);
        }
    }
}

// ---------------- reduce + transpose (fallback path) ----------------
__global__ __launch_bounds__(256)
void reduce_t_kernel(const float* __restrict__ vIn, int nIn,
                     float* __restrict__ vT)   // [8192][64]
{
    __shared__ float vt[64][68];
    const int tid = threadIdx.x;
    const int b0 = blockIdx.x * 64;   // grid 128
    #pragma unroll
    for (int k = 0; k < 8; ++k) {
        const int p  = (tid >> 5) + k * 8;
        const int bl = (tid & 31) * 2;
        float2 s = {0.f, 0.f};
        for (int g = 0; g < nIn; ++g) {
            const float2 u = *(const float2*)&vIn[(size_t)g * 524288
                                                  + (size_t)p * B_ALL + b0 + bl];
            s.x += u.x; s.y += u.y;
        }
        vt[bl][p] = s.x;
        vt[bl + 1][p] = s.y;
    }
    __syncthreads();
    const int b = tid >> 2, c = (tid & 3) * 16;
    float4* dst = (float4*)&vT[(size_t)(b0 + b) * 64 + c];
    #pragma unroll
    for (int q = 0; q < 4; ++q)
        dst[q] = *(float4*)&vt[b][c + q * 4];
}

// ---------------- final (fallback path) ----------------
__global__ __launch_bounds__(64)
void final_kernel(const __half* __restrict__ encH, const float* __restrict__ HL,
                  const float* __restrict__ vT, float* __restrict__ out)
{
    __shared__ float hl_s[64 * 129];
    const int tid = threadIdx.x;
    const int b0 = blockIdx.x * 16;
    for (int i = 0; i < 128; ++i) {
        const int idx = i * 64 + tid;
        hl_s[(idx >> 7) * 129 + (idx & 127)] = HL[idx];
    }
    __syncthreads();
    const int p = tid;
    for (int bs = 0; bs < 16; ++bs) {
        const int b = b0 + bs;
        const __half* er = encH + (size_t)(b * 12 + 11) * 128;
        float L = 0.0f;
        #pragma unroll 16
        for (int e = 0; e < 128; ++e)
            L += __half2float(er[e]) * hl_s[p * 129 + e];
        float pre = vT[(size_t)b * 64 + p] * L;
        #pragma unroll
        for (int off = 32; off > 0; off >>= 1)
            pre += __shfl_down(pre, off);
        if (tid == 0) out[b] = pre;
    }
}

// ---------------- persistent fused chain ----------------
// Barrier v3: hierarchical monotonic arrival + throttled polling.
//  - 64 group counters, 128B apart (8 blocks/group): same-line RMW queue
//    depth 8 instead of 512; total RMWs/barrier 128 instead of 512.
//  - monotonic ((a&7)==7, (r&63)==63): no resets -> no reset race, no
//    ordering waitcnt needed.
//  - pollers: relaxed sc1 load + s_sleep(32) (~0.85us) -> ~8x less MALL
//    pressure than sleep(4).
//  - data release: __syncthreads drains vmcnt(0) (sc1 stores at MALL);
//    modification-order chain grp->root->gen orders data before gen bump.
#define NB_FUSED 512

__device__ unsigned int g_grp[64 * 32];   // one counter per 128 B
__device__ unsigned int g_root = 0u;
__device__ unsigned int g_gen  = 0u;

__device__ __forceinline__ void grid_sync_fused() {
    __syncthreads();   // drains vmcnt(0): all waves' sc1 stores completed
    if (threadIdx.x == 0) {
        const unsigned g =
            __hip_atomic_load(&g_gen, __ATOMIC_RELAXED, __HIP_MEMORY_SCOPE_AGENT);
        const unsigned a =
            __hip_atomic_fetch_add(&g_grp[(blockIdx.x >> 3) * 32], 1u,
                                   __ATOMIC_RELAXED, __HIP_MEMORY_SCOPE_AGENT);
        if ((a & 7u) == 7u) {
            const unsigned r =
                __hip_atomic_fetch_add(&g_root, 1u, __ATOMIC_RELAXED,
                                       __HIP_MEMORY_SCOPE_AGENT);
            if ((r & 63u) == 63u) {
                __hip_atomic_store(&g_gen, g + 1u, __ATOMIC_RELAXED,
                                   __HIP_MEMORY_SCOPE_AGENT);
            }
        }
        while (__hip_atomic_load(&g_gen, __ATOMIC_RELAXED,
                                 __HIP_MEMORY_SCOPE_AGENT) == g)
            __builtin_amdgcn_s_sleep(32);
    }
    __syncthreads();
}

// r6 geometry: 512 blocks x 256 thr (4 waves: mf=wv>>1, bh=wv&1).
// Block = (btile: 128 b) x (eg: 16 e). 8 private partials [p][b], 2MB each.
__global__ __launch_bounds__(256, 2)
void fused_chain(const unsigned short* __restrict__ HmH,
                 const unsigned short* __restrict__ HmL,
                 const __half* __restrict__ encH,
                 const float* __restrict__ Hf,
                 const float* __restrict__ HL,
                 float* v0, float* pA, float* pB,
                 float* __restrict__ out)
{
    // LDS overlays: chain: vsum[64][132] (33792 B) + enc[16][132] (8448 B)
    //               init:  enc[64][129] (33024 B)
    //               final: hl[64][129] (33024 B) + vs[64][17] (4352 B)
    __shared__ __align__(16) unsigned char smem[42240];
    const int tid = threadIdx.x;
    const int bid = blockIdx.x;

    // ---- phase 0: init v0 (blocks 0..127, 64 b each) ----
    if (bid < 128) {
        float* encs = (float*)smem;        // [64][129]
        const int b0i = bid * 64;
        {
            const int b = tid >> 2, ec = (tid & 3) * 32;
            const __half* er = encH + ((size_t)(b0i + b) * 12 + 0) * 128 + ec;
            #pragma unroll
            for (int q = 0; q < 4; ++q) {
                uint4 u = *(const uint4*)(er + q * 8);
                const __half* hp = (const __half*)&u;
                #pragma unroll
                for (int j = 0; j < 8; ++j)
                    encs[b * 129 + ec + q * 8 + j] = __half2float(hp[j]);
            }
        }
        __syncthreads();
        const int wvi = tid >> 6, lanei = tid & 63;
        const int b = b0i + lanei;
        for (int pc = 0; pc < 16; pc += 4) {
            const int p = wvi * 16 + pc;
            float a0 = 0, a1 = 0, a2 = 0, a3 = 0;
            for (int e = 0; e < 128; ++e) {
                const float ev = encs[lanei * 129 + e];
                const float4 h = *(const float4*)&Hf[e * 64 + p];  // wave-uniform
                a0 += ev * h.x; a1 += ev * h.y; a2 += ev * h.z; a3 += ev * h.w;
            }
            st_f1_sc1(&v0[(size_t)(p + 0) * B_ALL + b], a0);
            st_f1_sc1(&v0[(size_t)(p + 1) * B_ALL + b], a1);
            st_f1_sc1(&v0[(size_t)(p + 2) * B_ALL + b], a2);
            st_f1_sc1(&v0[(size_t)(p + 3) * B_ALL + b], a3);
        }
    }
    grid_sync_fused();

    // ---- phases 1..10: chain ----
    const int b0 = (bid & 63) * 128;
    const int eg = bid >> 6;
    const int e0 = eg * 16;
    const int wv = tid >> 6, lane = tid & 63;
    const int l32 = lane & 31, half = lane >> 5;
    const int mf = wv >> 1, bh = wv & 1;

    float* vsum  = (float*)smem;               // [64][132]
    float* encs2 = (float*)(smem + 33792);     // [16][132]

    const float* vIn = v0;
    float* vOut = pA;
    const unsigned short* Hsh = HmH;
    const unsigned short* Hsl = HmL;

    #pragma unroll 1
    for (int t = 1; t <= 10; ++t) {
        // stage vsum = sum of partials (sc1 loads; 8-way unrolled for ILP)
        if (t == 1) {
            #pragma unroll
            for (int k = 0; k < 8; ++k) {
                const int p  = (tid >> 5) + k * 8;
                const int bl = (tid & 31) * 4;
                const float* base = &vIn[(size_t)p * B_ALL + b0 + bl];
                const float2 u0 = ld_f2_sc1(base);
                const float2 u1 = ld_f2_sc1(base + 2);
                *(float2*)&vsum[p * 132 + bl]     = u0;
                *(float2*)&vsum[p * 132 + bl + 2] = u1;
            }
        } else {
            #pragma unroll
            for (int k = 0; k < 8; ++k) {
                const int p  = (tid >> 5) + k * 8;
                const int bl = (tid & 31) * 4;
                float2 s01 = {0.f, 0.f}, s23 = {0.f, 0.f};
                #pragma unroll
                for (int g = 0; g < 8; ++g) {
                    const float* base = &vIn[(size_t)g * 524288
                                             + (size_t)p * B_ALL + b0 + bl];
                    const float2 u0 = ld_f2_sc1(base);
                    const float2 u1 = ld_f2_sc1(base + 2);
                    s01.x += u0.x; s01.y += u0.y;
                    s23.x += u1.x; s23.y += u1.y;
                }
                *(float2*)&vsum[p * 132 + bl]     = s01;
                *(float2*)&vsum[p * 132 + bl + 2] = s23;
            }
        }
        // stage enc slice [16 e][128 b]
        if (tid < 128) {
            const __half* er = encH + ((size_t)(b0 + tid) * 12 + t) * 128 + e0;
            uint4 u0 = *(const uint4*)er;
            uint4 u1 = *(const uint4*)(er + 8);
            const __half* h0 = (const __half*)&u0;
            const __half* h1 = (const __half*)&u1;
            #pragma unroll
            for (int el = 0; el < 8; ++el)
                encs2[el * 132 + tid] = __half2float(h0[el]);
            #pragma unroll
            for (int el = 0; el < 8; ++el)
                encs2[(el + 8) * 132 + tid] = __half2float(h1[el]);
        }
        __syncthreads();

        // B-frags: v hi/lo split from LDS (held in registers)
        bfrag vbh_[2][4], vbl_[2][4];
        #pragma unroll
        for (int nf = 0; nf < 2; ++nf) {
            const int bcol = bh * 64 + nf * 32 + l32;
            #pragma unroll
            for (int s = 0; s < 4; ++s) {
                const int p0 = s * 16 + half * 8;
                bfrag hb, lb;
                #pragma unroll
                for (int j = 0; j < 8; ++j) {
                    const float f = vsum[(p0 + j) * 132 + bcol];
                    const unsigned short hi = bf16_rne(f);
                    const unsigned short lo = bf16_rne(f - bf16_f32(hi));
                    hb[j] = (short)hi;
                    lb[j] = (short)lo;
                }
                vbh_[nf][s] = hb;
                vbl_[nf][s] = lb;
            }
        }

        ffrag z = 0.0f;
        ffrag vn0 = 0.0f, vn1 = 0.0f;

        #pragma unroll 2
        for (int e = 0; e < 16; ++e) {
            const float ev0 = encs2[e * 132 + bh * 64 + l32];
            const float ev1 = encs2[e * 132 + bh * 64 + 32 + l32];
            const unsigned short* hbase = Hsh + (size_t)(e0 + e) * 4096;
            const unsigned short* lbase = Hsl + (size_t)(e0 + e) * 4096;
            ffrag wa = z, wb = z;
            #pragma unroll
            for (int s = 0; s < 4; ++s) {
                const int fo = (((mf * 4 + s) * 2 + half) * 32 + l32) * 8;
                const bfrag ah = *(const bfrag*)(hbase + fo);
                const bfrag al = *(const bfrag*)(lbase + fo);
                wa = __builtin_amdgcn_mfma_f32_32x32x16_bf16(ah, vbh_[0][s], wa, 0, 0, 0);
                wa = __builtin_amdgcn_mfma_f32_32x32x16_bf16(ah, vbl_[0][s], wa, 0, 0, 0);
                wa = __builtin_amdgcn_mfma_f32_32x32x16_bf16(al, vbh_[0][s], wa, 0, 0, 0);
                wb = __builtin_amdgcn_mfma_f32_32x32x16_bf16(ah, vbh_[1][s], wb, 0, 0, 0);
                wb = __builtin_amdgcn_mfma_f32_32x32x16_bf16(ah, vbl_[1][s], wb, 0, 0, 0);
                wb = __builtin_amdgcn_mfma_f32_32x32x16_bf16(al, vbh_[1][s], wb, 0, 0, 0);
            }
            vn0 += wa * ev0;
            vn1 += wb * ev1;
        }

        // epilogue: private partial slice (sc1 stores, coalesced per half-wave)
        #pragma unroll
        for (int nf = 0; nf < 2; ++nf) {
            const ffrag vv = nf ? vn1 : vn0;
            const int b = b0 + bh * 64 + nf * 32 + l32;
            #pragma unroll
            for (int i = 0; i < 16; ++i) {
                const int r = mf * 32 + (i & 3) + 8 * (i >> 2) + 4 * half;
                st_f1_sc1(&vOut[(size_t)eg * 524288 + (size_t)r * B_ALL + b],
                          vv[i]);
            }
        }

        grid_sync_fused();

        vIn = vOut;
        vOut = (t & 1) ? pB : pA;
        Hsh += 524288;
        Hsl += 524288;
    }

    // ---- final: all 512 blocks, 16 b each; sum 8 partials in LDS ----
    {
        float* hl_s = (float*)smem;              // [64][129]
        float* vs   = (float*)(smem + 33024);    // [64][17]
        const float* vFin = pB;                  // t=10 (even) wrote pB
        const int fb0 = bid * 16;
        #pragma unroll
        for (int i = 0; i < 32; ++i) {
            const int idx = i * 256 + tid;       // 8192 floats of HL
            hl_s[(idx >> 7) * 129 + (idx & 127)] = HL[idx];
        }
        {
            const int p  = tid >> 2;
            const int bs = (tid & 3) * 4;
            float4 s = {0.f, 0.f, 0.f, 0.f};
            #pragma unroll
            for (int g = 0; g < 8; ++g) {
                const float* base = &vFin[(size_t)g * 524288
                                          + (size_t)p * B_ALL + fb0 + bs];
                const float2 u0 = ld_f2_sc1(base);
                const float2 u1 = ld_f2_sc1(base + 2);
                s.x += u0.x; s.y += u0.y; s.z += u1.x; s.w += u1.y;
            }
            vs[p * 17 + bs + 0] = s.x;
            vs[p * 17 + bs + 1] = s.y;
            vs[p * 17 + bs + 2] = s.z;
            vs[p * 17 + bs + 3] = s.w;
        }
        __syncthreads();
        const int wv2 = tid >> 6, lane2 = tid & 63;
        #pragma unroll
        for (int q = 0; q < 4; ++q) {
            const int bl = wv2 * 4 + q;
            const __half* er = encH + ((size_t)(fb0 + bl) * 12 + 11) * 128;
            float L = 0.0f;
            #pragma unroll 16
            for (int e = 0; e < 128; ++e)
                L += __half2float(er[e]) * hl_s[lane2 * 129 + e];
            float pre = vs[lane2 * 17 + bl] * L;
            #pragma unroll
            for (int off = 32; off > 0; off >>= 1)
                pre += __shfl_down(pre, off);
            if (lane2 == 0) out[fb0 + bl] = pre;
        }
    }
}

extern "C" void kernel_launch(void* const* d_in, const int* in_sizes, int n_in,
                              void* d_out, int out_size, void* d_ws, size_t ws_size,
                              hipStream_t stream) {
    const float* x  = (const float*)d_in[0];
    const float* W1 = (const float*)d_in[1];
    const float* b1 = (const float*)d_in[2];
    const float* W2 = (const float*)d_in[3];
    const float* b2 = (const float*)d_in[4];
    const float* Hf = (const float*)d_in[5];
    const float* Hm = (const float*)d_in[6];
    const float* HL = (const float*)d_in[7];
    float* out = (float*)d_out;
    (void)in_sizes; (void)n_in; (void)out_size;

    char* ws = (char*)d_ws;
    __half* encH        = (__half*)(ws + O_ENC);
    unsigned short* HmH = (unsigned short*)(ws + O_HMH);
    unsigned short* HmL = (unsigned short*)(ws + O_HML);
    __half* w1f         = (__half*)(ws + O_W1F);
    __half* w2f         = (__half*)(ws + O_W2F);
    float* v0           = (float*)(ws + O_V0);
    float* vT           = (float*)(ws + O_V0);   // fallback alias

    const bool part = (ws_size >= NEED_PARTIAL);

    prep_kernel<<<dim3(5216), dim3(256), 0, stream>>>(W1, W2, Hm, w1f, w2f, HmH, HmL);
    enc_kernel<<<dim3(1536), dim3(256), 0, stream>>>(x, b1, b2, w1f, w2f, encH);

    if (part) {
        float* pA = (float*)(ws + O_PA);
        float* pB = (float*)(ws + O_PB);
        fused_chain<<<dim3(512), dim3(256), 0, stream>>>(
            HmH, HmL, encH, Hf, HL, v0, pA, pB, out);
    } else {
        init_kernel<<<dim3(128), dim3(256), 0, stream>>>(encH, Hf, v0);
        float* vA = (float*)(ws + O_VA);
        float* vB = (float*)(ws + O_VB);
        const float* cur = v0;
        for (int t = 1; t <= 10; ++t) {
            float* nxt = (t & 1) ? vA : vB;
            hipMemsetAsync(nxt, 0, (size_t)64 * B_ALL * sizeof(float), stream);
            chain_step<<<dim3(512), dim3(256), 0, stream>>>(
                HmH + (size_t)(t - 1) * 524288, HmL + (size_t)(t - 1) * 524288,
                encH, cur, 1, nxt, 0, t);
            cur = nxt;
        }
        reduce_t_kernel<<<dim3(128), dim3(256), 0, stream>>>(cur, 1, vT);
        final_kernel<<<dim3(512), dim3(64), 0, stream>>>(encH, HL, vT, out);
    }
}